// Round 2
// baseline (7239.718 us; speedup 1.0000x reference)
//
#include <hip/hip_runtime.h>

#define NCAND 50000
#define NB    512
#define DIN   820
#define DM    512
#define DBK   1024
#define NFEAT 50
#define NCAT  20
#define NFREQ 16
#define DEMB  16
#define CTX   96

static __device__ __forceinline__ unsigned short f2bf(float f) {
    union { float f; unsigned int i; } u; u.f = f;
    unsigned int r = u.i + 0x7FFFu + ((u.i >> 16) & 1u);
    return (unsigned short)(r >> 16);
}
static __device__ __forceinline__ float bf2f(unsigned short s) {
    union { unsigned int i; float f; } u; u.i = ((unsigned int)s) << 16;
    return u.f;
}

// ---------------------------------------------------------------- PLR encode
// rows [0,nrows) of xn (nrows x 50) / xc (nrows x 20) -> out (nrows x 820)
__global__ __launch_bounds__(256) void plr_kernel(
    const float* __restrict__ xn_, const float* __restrict__ xc_, int nrows,
    const float* __restrict__ freq, const float* __restrict__ plr_w,
    const float* __restrict__ plr_b, float* __restrict__ out)
{
    __shared__ float sW[32 * 16];
    __shared__ float sB[16];
    __shared__ float sF[NFEAT * NFREQ];
    int tid = threadIdx.x;
    for (int i = tid; i < 512; i += 256) sW[i] = plr_w[i];
    if (tid < 16) sB[tid] = plr_b[tid];
    for (int i = tid; i < NFEAT * NFREQ; i += 256) sF[i] = freq[i];
    __syncthreads();
    int wave = tid >> 6, lane = tid & 63;
    int row = blockIdx.x * 4 + wave;
    if (row >= nrows) return;
    const float* xn = xn_ + (size_t)row * NFEAT;
    const float* xc = xc_ + (size_t)row * NCAT;
    float* o = out + (size_t)row * DIN;
    if (lane < NFEAT) {
        float x = xn[lane];
        float cs[NFREQ], sn[NFREQ];
        #pragma unroll
        for (int j = 0; j < NFREQ; j++) {
            float p = 6.28318530717958647692f * sF[lane * NFREQ + j] * x;
            sn[j] = __sinf(p);
            cs[j] = __cosf(p);
        }
        float r16[16];
        #pragma unroll
        for (int d = 0; d < DEMB; d++) {
            float acc = sB[d];
            #pragma unroll
            for (int j = 0; j < NFREQ; j++)
                acc = fmaf(cs[j], sW[j * DEMB + d], fmaf(sn[j], sW[(NFREQ + j) * DEMB + d], acc));
            r16[d] = fmaxf(acc, 0.f);
        }
        float4* po = (float4*)(o + lane * DEMB);
        po[0] = make_float4(r16[0], r16[1], r16[2], r16[3]);
        po[1] = make_float4(r16[4], r16[5], r16[6], r16[7]);
        po[2] = make_float4(r16[8], r16[9], r16[10], r16[11]);
        po[3] = make_float4(r16[12], r16[13], r16[14], r16[15]);
    }
    if (lane < NCAT) o[800 + lane] = xc[lane];
}

// ------------------------------------------------- fp32 GEMM  C = A@W (+bias)(+res)(relu)
// A: M x K row-major, W: K x N row-major, N % 128 == 0. out_bf16: store C as bf16.
__global__ __launch_bounds__(256) void sgemm_kernel(
    const float* __restrict__ A, const float* __restrict__ W,
    float* C, int M, int N, int K,
    const float* __restrict__ bias, const float* res, int do_relu, int out_bf16)
{
    __shared__ float As[8][132];
    __shared__ float Ws[8][132];
    int tid = threadIdx.x;
    int bm = blockIdx.y * 128;
    int bn = blockIdx.x * 128;
    int tx = tid & 15, ty = tid >> 4;
    float acc[8][8];
    #pragma unroll
    for (int i = 0; i < 8; i++)
        #pragma unroll
        for (int j = 0; j < 8; j++) acc[i][j] = 0.f;

    int a_row = tid >> 1;
    int a_k4  = (tid & 1) * 4;
    int w_k   = tid >> 5;
    int w_n   = (tid & 31) * 4;

    for (int k0 = 0; k0 < K; k0 += 8) {
        float4 av = make_float4(0.f, 0.f, 0.f, 0.f);
        {
            int gm = bm + a_row, gk = k0 + a_k4;
            if (gm < M) {
                const float* p = A + (size_t)gm * K;
                if (gk + 4 <= K) av = *(const float4*)(p + gk);
                else {
                    if (gk + 0 < K) av.x = p[gk + 0];
                    if (gk + 1 < K) av.y = p[gk + 1];
                    if (gk + 2 < K) av.z = p[gk + 2];
                    if (gk + 3 < K) av.w = p[gk + 3];
                }
            }
        }
        float4 wv = make_float4(0.f, 0.f, 0.f, 0.f);
        {
            int gk = k0 + w_k, gn = bn + w_n;
            if (gk < K) wv = *(const float4*)(W + (size_t)gk * N + gn);
        }
        __syncthreads();
        As[a_k4 + 0][a_row] = av.x;
        As[a_k4 + 1][a_row] = av.y;
        As[a_k4 + 2][a_row] = av.z;
        As[a_k4 + 3][a_row] = av.w;
        *(float4*)&Ws[w_k][w_n] = wv;
        __syncthreads();
        #pragma unroll
        for (int kk = 0; kk < 8; kk++) {
            float4 a0 = *(const float4*)&As[kk][ty * 4];
            float4 a1 = *(const float4*)&As[kk][64 + ty * 4];
            float4 b0 = *(const float4*)&Ws[kk][tx * 4];
            float4 b1 = *(const float4*)&Ws[kk][64 + tx * 4];
            float aa[8] = {a0.x, a0.y, a0.z, a0.w, a1.x, a1.y, a1.z, a1.w};
            float bb[8] = {b0.x, b0.y, b0.z, b0.w, b1.x, b1.y, b1.z, b1.w};
            #pragma unroll
            for (int i = 0; i < 8; i++)
                #pragma unroll
                for (int j = 0; j < 8; j++)
                    acc[i][j] = fmaf(aa[i], bb[j], acc[i][j]);
        }
    }
    #pragma unroll
    for (int ih = 0; ih < 2; ih++)
    #pragma unroll
    for (int ii = 0; ii < 4; ii++) {
        int m = bm + ih * 64 + ty * 4 + ii;
        if (m >= M) continue;
        #pragma unroll
        for (int jh = 0; jh < 2; jh++) {
            int n = bn + jh * 64 + tx * 4;
            float v0 = acc[ih * 4 + ii][jh * 4 + 0];
            float v1 = acc[ih * 4 + ii][jh * 4 + 1];
            float v2 = acc[ih * 4 + ii][jh * 4 + 2];
            float v3 = acc[ih * 4 + ii][jh * 4 + 3];
            if (bias) { v0 += bias[n]; v1 += bias[n + 1]; v2 += bias[n + 2]; v3 += bias[n + 3]; }
            if (res) {
                const float* r = res + (size_t)m * N + n;
                v0 += r[0]; v1 += r[1]; v2 += r[2]; v3 += r[3];
            }
            if (do_relu) {
                v0 = fmaxf(v0, 0.f); v1 = fmaxf(v1, 0.f);
                v2 = fmaxf(v2, 0.f); v3 = fmaxf(v3, 0.f);
            }
            if (out_bf16) {
                unsigned short* cb = (unsigned short*)C + (size_t)m * N + n;
                ushort4 o;
                o.x = f2bf(v0); o.y = f2bf(v1); o.z = f2bf(v2); o.w = f2bf(v3);
                *(ushort4*)cb = o;
            } else {
                *(float4*)(C + (size_t)m * N + n) = make_float4(v0, v1, v2, v3);
            }
        }
    }
}

// ------------------------------------- NT GEMM scores strip: C = 2*A@B^T - cnorm[n]
// A: M x K, B: N x K, C: M x N (N = chunk rows, any multiple of anything)
__global__ __launch_bounds__(256) void sgemm_nt_kernel(
    const float* __restrict__ A, const float* __restrict__ B,
    float* __restrict__ C, int M, int N, int K,
    const float* __restrict__ cnorm)
{
    __shared__ float As[8][132];
    __shared__ float Bs[8][132];
    int tid = threadIdx.x;
    int bm = blockIdx.y * 128;
    int bn = blockIdx.x * 128;
    int tx = tid & 15, ty = tid >> 4;
    float acc[8][8];
    #pragma unroll
    for (int i = 0; i < 8; i++)
        #pragma unroll
        for (int j = 0; j < 8; j++) acc[i][j] = 0.f;

    int s_row = tid >> 1;
    int s_k4  = (tid & 1) * 4;

    for (int k0 = 0; k0 < K; k0 += 8) {
        float4 av = make_float4(0.f, 0.f, 0.f, 0.f);
        float4 bv = make_float4(0.f, 0.f, 0.f, 0.f);
        int gk = k0 + s_k4;
        {
            int gm = bm + s_row;
            if (gm < M) av = *(const float4*)(A + (size_t)gm * K + gk);
        }
        {
            int gn = bn + s_row;
            if (gn < N) bv = *(const float4*)(B + (size_t)gn * K + gk);
        }
        __syncthreads();
        As[s_k4 + 0][s_row] = av.x;
        As[s_k4 + 1][s_row] = av.y;
        As[s_k4 + 2][s_row] = av.z;
        As[s_k4 + 3][s_row] = av.w;
        Bs[s_k4 + 0][s_row] = bv.x;
        Bs[s_k4 + 1][s_row] = bv.y;
        Bs[s_k4 + 2][s_row] = bv.z;
        Bs[s_k4 + 3][s_row] = bv.w;
        __syncthreads();
        #pragma unroll
        for (int kk = 0; kk < 8; kk++) {
            float4 a0 = *(const float4*)&As[kk][ty * 4];
            float4 a1 = *(const float4*)&As[kk][64 + ty * 4];
            float4 b0 = *(const float4*)&Bs[kk][tx * 4];
            float4 b1 = *(const float4*)&Bs[kk][64 + tx * 4];
            float aa[8] = {a0.x, a0.y, a0.z, a0.w, a1.x, a1.y, a1.z, a1.w};
            float bb[8] = {b0.x, b0.y, b0.z, b0.w, b1.x, b1.y, b1.z, b1.w};
            #pragma unroll
            for (int i = 0; i < 8; i++)
                #pragma unroll
                for (int j = 0; j < 8; j++)
                    acc[i][j] = fmaf(aa[i], bb[j], acc[i][j]);
        }
    }
    #pragma unroll
    for (int ih = 0; ih < 2; ih++)
    #pragma unroll
    for (int ii = 0; ii < 4; ii++) {
        int m = bm + ih * 64 + ty * 4 + ii;
        if (m >= M) continue;
        #pragma unroll
        for (int jh = 0; jh < 2; jh++) {
            int n = bn + jh * 64 + tx * 4;
            float* cp = C + (size_t)m * N + n;
            #pragma unroll
            for (int jj = 0; jj < 4; jj++) {
                if (n + jj < N)
                    cp[jj] = 2.f * acc[ih * 4 + ii][jh * 4 + jj] - cnorm[n + jj];
            }
        }
    }
}

// ---------------------------------------------------------------- LayerNorm (rows of 512)
__global__ __launch_bounds__(256) void ln_kernel(const float* __restrict__ X,
    float* __restrict__ Y, const float* __restrict__ g, const float* __restrict__ bt, int M)
{
    int wave = threadIdx.x >> 6, lane = threadIdx.x & 63;
    int row = blockIdx.x * 4 + wave;
    if (row >= M) return;
    const float* x = X + (size_t)row * DM;
    float4 v0 = ((const float4*)x)[lane * 2];
    float4 v1 = ((const float4*)x)[lane * 2 + 1];
    float s = v0.x + v0.y + v0.z + v0.w + v1.x + v1.y + v1.z + v1.w;
    #pragma unroll
    for (int off = 32; off; off >>= 1) s += __shfl_xor(s, off, 64);
    float m = s * (1.f / DM);
    float q = (v0.x - m) * (v0.x - m) + (v0.y - m) * (v0.y - m)
            + (v0.z - m) * (v0.z - m) + (v0.w - m) * (v0.w - m)
            + (v1.x - m) * (v1.x - m) + (v1.y - m) * (v1.y - m)
            + (v1.z - m) * (v1.z - m) + (v1.w - m) * (v1.w - m);
    #pragma unroll
    for (int off = 32; off; off >>= 1) q += __shfl_xor(q, off, 64);
    float rstd = 1.f / sqrtf(q * (1.f / DM) + 1e-5f);
    float4 g0 = ((const float4*)g)[lane * 2], g1 = ((const float4*)g)[lane * 2 + 1];
    float4 b0 = ((const float4*)bt)[lane * 2], b1 = ((const float4*)bt)[lane * 2 + 1];
    float4 y0 = make_float4((v0.x - m) * rstd * g0.x + b0.x, (v0.y - m) * rstd * g0.y + b0.y,
                            (v0.z - m) * rstd * g0.z + b0.z, (v0.w - m) * rstd * g0.w + b0.w);
    float4 y1 = make_float4((v1.x - m) * rstd * g1.x + b1.x, (v1.y - m) * rstd * g1.y + b1.y,
                            (v1.z - m) * rstd * g1.z + b1.z, (v1.w - m) * rstd * g1.w + b1.w);
    float* y = Y + (size_t)row * DM;
    ((float4*)y)[lane * 2] = y0;
    ((float4*)y)[lane * 2 + 1] = y1;
}

// ---------------------------------------------------------------- key norms
__global__ __launch_bounds__(256) void cnorm_kernel(const float* __restrict__ Kc,
    float* __restrict__ cn, int N)
{
    int wave = threadIdx.x >> 6, lane = threadIdx.x & 63;
    int row = blockIdx.x * 4 + wave;
    if (row >= N) return;
    const float* x = Kc + (size_t)row * DM;
    float4 v0 = ((const float4*)x)[lane * 2];
    float4 v1 = ((const float4*)x)[lane * 2 + 1];
    float s = v0.x * v0.x + v0.y * v0.y + v0.z * v0.z + v0.w * v0.w
            + v1.x * v1.x + v1.y * v1.y + v1.z * v1.z + v1.w * v1.w;
    #pragma unroll
    for (int off = 32; off; off >>= 1) s += __shfl_xor(s, off, 64);
    if (lane == 0) cn[row] = s;
}

// ---------------------------------------------------------------- ctx init
__global__ void ctx_init_kernel(int* __restrict__ idx, float* __restrict__ sc)
{
    int i = blockIdx.x * 256 + threadIdx.x;
    if (i < NB * CTX) { idx[i] = 0; sc[i] = -1e30f; }
}

// ------------------------------------- running top-96 merge (chunk scores + prev)
#define NBINS 4096
#define CANDCAP 2048
__global__ __launch_bounds__(256) void topk_merge_kernel(
    const float* __restrict__ S, int m, int base,
    const int* __restrict__ pidx, const float* __restrict__ pscore,
    int* __restrict__ nidx, float* __restrict__ nscore)
{
    __shared__ int   hist[NBINS];
    __shared__ float red[256];
    __shared__ float prev_s[CTX];
    __shared__ int   prev_i[CTX];
    __shared__ float s_mn, s_scale;
    __shared__ int   s_bstar, s_m, nsel, ncnd;
    __shared__ float cnd_s[CANDCAP];
    __shared__ int   cnd_g[CANDCAP];
    __shared__ float sel_s[CTX];
    __shared__ int   sel_g[CTX];

    int b = blockIdx.x, tid = threadIdx.x;
    const float* Sb = S + (size_t)b * m;
    if (tid < CTX) { prev_s[tid] = pscore[b * CTX + tid]; prev_i[tid] = pidx[b * CTX + tid]; }
    for (int i = tid; i < NBINS; i += 256) hist[i] = 0;
    __syncthreads();
    int tot = m + CTX;
    float mn = 1e30f, mx = -1e30f;
    for (int i = tid; i < tot; i += 256) {
        float v = (i < m) ? Sb[i] : prev_s[i - m];
        if (v > -1e29f) { mn = fminf(mn, v); mx = fmaxf(mx, v); }
    }
    red[tid] = mx; __syncthreads();
    for (int s = 128; s > 0; s >>= 1) { if (tid < s) red[tid] = fmaxf(red[tid], red[tid + s]); __syncthreads(); }
    float gmx = red[0]; __syncthreads();
    red[tid] = mn; __syncthreads();
    for (int s = 128; s > 0; s >>= 1) { if (tid < s) red[tid] = fminf(red[tid], red[tid + s]); __syncthreads(); }
    float gmn = red[0]; __syncthreads();
    if (tid == 0) {
        float w = gmx - gmn;
        if (!(w > 0.f)) w = 1.f;
        s_mn = gmn;
        s_scale = (float)NBINS / w * 0.9999990f;
        nsel = 0; ncnd = 0;
    }
    __syncthreads();
    float lmn = s_mn, lsc = s_scale;
    for (int i = tid; i < tot; i += 256) {
        float v = (i < m) ? Sb[i] : prev_s[i - m];
        if (v <= -1e29f) continue;
        int bin = (int)((v - lmn) * lsc);
        bin = max(0, min(NBINS - 1, bin));
        atomicAdd(&hist[bin], 1);
    }
    __syncthreads();
    if (tid == 0) {
        int cum = 0, bb = 0;
        for (int i = NBINS - 1; i >= 0; i--) {
            int h = hist[i];
            if (cum + h >= CTX) { bb = i; break; }
            cum += h;
        }
        s_bstar = bb; s_m = CTX - cum;
    }
    __syncthreads();
    int bstar = s_bstar;
    for (int i = tid; i < tot; i += 256) {
        float v = (i < m) ? Sb[i] : prev_s[i - m];
        if (v <= -1e29f) continue;
        int g = (i < m) ? (base + i) : prev_i[i - m];
        int bin = (int)((v - lmn) * lsc);
        bin = max(0, min(NBINS - 1, bin));
        if (bin > bstar) {
            int p = atomicAdd(&nsel, 1);
            sel_s[p] = v; sel_g[p] = g;
        } else if (bin == bstar) {
            int p = atomicAdd(&ncnd, 1);
            if (p < CANDCAP) { cnd_s[p] = v; cnd_g[p] = g; }
        }
    }
    __syncthreads();
    int msel = s_m;
    int nc = min(ncnd, CANDCAP);
    for (int i = tid; i < nc; i += 256) {
        float si = cnd_s[i]; int gi = cnd_g[i];
        int rank = 0;
        for (int j = 0; j < nc; j++) {
            float sj = cnd_s[j];
            rank += (sj > si) || (sj == si && cnd_g[j] < gi);
        }
        if (rank < msel) {
            int p = atomicAdd(&nsel, 1);
            sel_s[p] = si; sel_g[p] = gi;
        }
    }
    __syncthreads();
    if (tid < CTX) {
        nidx[b * CTX + tid] = sel_g[tid];
        nscore[b * CTX + tid] = sel_s[tid];
    }
}

// ------------------------------- softmax + label/value context aggregation
__global__ __launch_bounds__(256) void agg_kernel(
    const int* __restrict__ ctx_idx, const float* __restrict__ ctx_score,
    const float* __restrict__ cand_y, const float* __restrict__ T1b,
    const unsigned short* __restrict__ T1c, const float* __restrict__ T_b1,
    const float* __restrict__ x_batch,
    const float* __restrict__ label_w, const float* __restrict__ label_b,
    float* __restrict__ s_out, float* __restrict__ u_out)
{
    __shared__ float p_s[CTX];
    __shared__ int   p_i[CTX];
    __shared__ float s_ybar;
    int b = blockIdx.x, tid = threadIdx.x;
    if (tid < CTX) { p_s[tid] = ctx_score[b * CTX + tid]; p_i[tid] = ctx_idx[b * CTX + tid]; }
    __syncthreads();
    if (tid == 0) {
        float mx = -1e30f;
        for (int c = 0; c < CTX; c++) mx = fmaxf(mx, p_s[c]);
        float sum = 0.f;
        for (int c = 0; c < CTX; c++) { float e = __expf(p_s[c] - mx); p_s[c] = e; sum += e; }
        float inv = 1.f / sum, yb = 0.f;
        for (int c = 0; c < CTX; c++) { p_s[c] *= inv; yb += p_s[c] * cand_y[p_i[c]]; }
        s_ybar = yb;
    }
    __syncthreads();
    int j = tid * 4;
    float4 kv = *(const float4*)(T1b + (size_t)b * DBK + j);
    float4 tb = *(const float4*)(T_b1 + j);
    float base0 = kv.x + tb.x, base1 = kv.y + tb.y, base2 = kv.z + tb.z, base3 = kv.w + tb.w;
    float a0 = 0.f, a1 = 0.f, a2 = 0.f, a3 = 0.f;
    for (int c = 0; c < CTX; c++) {
        float p = p_s[c];
        ushort4 cu = *(const ushort4*)(T1c + (size_t)p_i[c] * DBK + j);
        a0 = fmaf(p, fmaxf(base0 - bf2f(cu.x), 0.f), a0);
        a1 = fmaf(p, fmaxf(base1 - bf2f(cu.y), 0.f), a1);
        a2 = fmaf(p, fmaxf(base2 - bf2f(cu.z), 0.f), a2);
        a3 = fmaf(p, fmaxf(base3 - bf2f(cu.w), 0.f), a3);
    }
    *(float4*)(s_out + (size_t)b * DBK + j) = make_float4(a0, a1, a2, a3);
    if (tid < 128) {
        int d = tid * 4;
        float4 xv = *(const float4*)(x_batch + (size_t)b * DM + d);
        float4 lw = *(const float4*)(label_w + d);
        float4 lb = *(const float4*)(label_b + d);
        float yb = s_ybar;
        *(float4*)(u_out + (size_t)b * DM + d) =
            make_float4(xv.x + yb * lw.x + lb.x, xv.y + yb * lw.y + lb.y,
                        xv.z + yb * lw.z + lb.z, xv.w + yb * lw.w + lb.w);
    }
}

// ---------------------------------------------------------------- head
__global__ __launch_bounds__(256) void head_kernel(
    const float* __restrict__ X, const float* __restrict__ g,
    const float* __restrict__ bt, const float* __restrict__ w,
    const float* __restrict__ hb, float* __restrict__ out, int M)
{
    int wave = threadIdx.x >> 6, lane = threadIdx.x & 63;
    int row = blockIdx.x * 4 + wave;
    if (row >= M) return;
    const float* x = X + (size_t)row * DM;
    float4 v0 = ((const float4*)x)[lane * 2];
    float4 v1 = ((const float4*)x)[lane * 2 + 1];
    float s = v0.x + v0.y + v0.z + v0.w + v1.x + v1.y + v1.z + v1.w;
    #pragma unroll
    for (int off = 32; off; off >>= 1) s += __shfl_xor(s, off, 64);
    float m = s * (1.f / DM);
    float q = (v0.x - m) * (v0.x - m) + (v0.y - m) * (v0.y - m)
            + (v0.z - m) * (v0.z - m) + (v0.w - m) * (v0.w - m)
            + (v1.x - m) * (v1.x - m) + (v1.y - m) * (v1.y - m)
            + (v1.z - m) * (v1.z - m) + (v1.w - m) * (v1.w - m);
    #pragma unroll
    for (int off = 32; off; off >>= 1) q += __shfl_xor(q, off, 64);
    float rstd = 1.f / sqrtf(q * (1.f / DM) + 1e-5f);
    float4 g0 = ((const float4*)g)[lane * 2], g1 = ((const float4*)g)[lane * 2 + 1];
    float4 b0 = ((const float4*)bt)[lane * 2], b1 = ((const float4*)bt)[lane * 2 + 1];
    float4 w0 = ((const float4*)w)[lane * 2], w1 = ((const float4*)w)[lane * 2 + 1];
    float t = 0.f;
    t += fmaxf((v0.x - m) * rstd * g0.x + b0.x, 0.f) * w0.x;
    t += fmaxf((v0.y - m) * rstd * g0.y + b0.y, 0.f) * w0.y;
    t += fmaxf((v0.z - m) * rstd * g0.z + b0.z, 0.f) * w0.z;
    t += fmaxf((v0.w - m) * rstd * g0.w + b0.w, 0.f) * w0.w;
    t += fmaxf((v1.x - m) * rstd * g1.x + b1.x, 0.f) * w1.x;
    t += fmaxf((v1.y - m) * rstd * g1.y + b1.y, 0.f) * w1.y;
    t += fmaxf((v1.z - m) * rstd * g1.z + b1.z, 0.f) * w1.z;
    t += fmaxf((v1.w - m) * rstd * g1.w + b1.w, 0.f) * w1.w;
    #pragma unroll
    for (int off = 32; off; off >>= 1) t += __shfl_xor(t, off, 64);
    if (lane == 0) out[row] = t + hb[0];
}

// =================================================================== host
extern "C" void kernel_launch(void* const* d_in, const int* in_sizes, int n_in,
                              void* d_out, int out_size, void* d_ws, size_t ws_size,
                              hipStream_t stream) {
    (void)in_sizes; (void)n_in; (void)out_size;
    const float* x_num   = (const float*)d_in[0];
    const float* x_cat   = (const float*)d_in[1];
    const float* cxn     = (const float*)d_in[2];
    const float* cxc     = (const float*)d_in[3];
    const float* cand_y  = (const float*)d_in[4];
    const float* freq    = (const float*)d_in[6];
    const float* plr_w   = (const float*)d_in[7];
    const float* plr_b   = (const float*)d_in[8];
    const float* lin_w   = (const float*)d_in[9];
    const float* lin_b   = (const float*)d_in[10];
    const float* enc_w1  = (const float*)d_in[11];
    const float* enc_b1  = (const float*)d_in[12];
    const float* enc_w2  = (const float*)d_in[13];
    const float* enc_b2  = (const float*)d_in[14];
    const float* mix_g   = (const float*)d_in[15];
    const float* mix_b   = (const float*)d_in[16];
    const float* K_w     = (const float*)d_in[17];
    const float* K_b     = (const float*)d_in[18];
    const float* label_w = (const float*)d_in[19];
    const float* label_b = (const float*)d_in[20];
    const float* T_w1    = (const float*)d_in[21];
    const float* T_b1    = (const float*)d_in[22];
    const float* T_w2    = (const float*)d_in[23];
    const float* pred_g  = (const float*)d_in[24];
    const float* pred_b  = (const float*)d_in[25];
    const float* pred_w1 = (const float*)d_in[26];
    const float* pred_b1 = (const float*)d_in[27];
    const float* pred_w2 = (const float*)d_in[28];
    const float* pred_b2 = (const float*)d_in[29];
    const float* head_g  = (const float*)d_in[30];
    const float* head_b  = (const float*)d_in[31];
    const float* head_w  = (const float*)d_in[32];
    const float* head_bias = (const float*)d_in[33];
    float* out = (float*)d_out;

    char* ws = (char*)d_ws;
    size_t off = 0;
    auto alloc = [&](size_t n) { char* p = ws + off; off = (off + n + 255) & ~(size_t)255; return p; };

    // --- persistent buffers (~112 MB) ---
    unsigned short* T1c = (unsigned short*)alloc((size_t)NCAND * DBK * 2); // 102.4 MB bf16
    float* T1b  = (float*)alloc((size_t)NB * DBK * 4);   // fp32 batch T1
    float* xB   = (float*)alloc((size_t)NB * DM * 4);
    float* kB   = (float*)alloc((size_t)NB * DM * 4);
    int*   ctxAi = (int*)alloc((size_t)NB * CTX * 4);
    float* ctxAs = (float*)alloc((size_t)NB * CTX * 4);
    int*   ctxBi = (int*)alloc((size_t)NB * CTX * 4);
    float* ctxBs = (float*)alloc((size_t)NB * CTX * 4);
    float* sbuf = (float*)alloc((size_t)NB * DBK * 4);
    float* ubuf = (float*)alloc((size_t)NB * DM * 4);
    float* x2   = (float*)alloc((size_t)NB * DM * 4);
    float* h2   = (float*)alloc((size_t)NB * DM * 4);
    float* hp   = (float*)alloc((size_t)NB * DBK * 4);
    float* x3   = (float*)alloc((size_t)NB * DM * 4);

    // --- chunk scratch, sized to remaining workspace ---
    size_t remain = (ws_size > off + 4096) ? (ws_size - off - 4096) : 0;
    const size_t perrow = (size_t)DIN * 4 + (size_t)DM * 4 + (size_t)DBK * 4 + 4; // 9428 B
    long ncl = (long)(remain / perrow);
    int NC = (int)(ncl > 6400 ? 6400 : ncl);
    NC &= ~127;
    if (NC < 128) NC = 128;
    float* inC = (float*)alloc((size_t)NC * DIN * 4);  // also holds scoresC (NB*NC*4 <= NC*DIN*4)
    float* xC  = (float*)alloc((size_t)NC * DM * 4);
    float* hC  = (float*)alloc((size_t)NC * DBK * 4);  // also holds kC (NC*DM*4)
    float* cnC = (float*)alloc((size_t)NC * 4);
    float* scoresC = inC;
    float* kC = hC;

    auto sgemm = [&](const float* A, const float* W, float* C, int M, int N, int K,
                     const float* bias, const float* res, int relu, int obf16) {
        dim3 grid((N + 127) / 128, (M + 127) / 128);
        sgemm_kernel<<<grid, 256, 0, stream>>>(A, W, C, M, N, K, bias, res, relu, obf16);
    };

    // ---------- batch encode (reuse sbuf as inB, hp as hB, h2 as lnB) ----------
    float* inB = sbuf;
    float* hB  = hp;
    float* lnB = h2;
    plr_kernel<<<(NB + 3) / 4, 256, 0, stream>>>(x_num, x_cat, NB, freq, plr_w, plr_b, inB);
    sgemm(inB, lin_w, xB, NB, DM, DIN, lin_b, nullptr, 0, 0);
    sgemm(xB, enc_w1, hB, NB, DBK, DM, enc_b1, nullptr, 1, 0);
    sgemm(hB, enc_w2, xB, NB, DM, DBK, enc_b2, xB, 0, 0);
    ln_kernel<<<(NB + 3) / 4, 256, 0, stream>>>(xB, lnB, mix_g, mix_b, NB);
    sgemm(lnB, K_w, kB, NB, DM, DM, K_b, nullptr, 0, 0);
    sgemm(kB, T_w1, T1b, NB, DBK, DM, nullptr, nullptr, 0, 0);
    ctx_init_kernel<<<(NB * CTX + 255) / 256, 256, 0, stream>>>(ctxAi, ctxAs);

    // ---------- candidate chunks ----------
    const int* pI = ctxAi; const float* pS = ctxAs;
    int* nI = ctxBi; float* nS = ctxBs;
    int nch = (NCAND + NC - 1) / NC;
    for (int c = 0; c < nch; c++) {
        int s = c * NC;
        int m = NCAND - s; if (m > NC) m = NC;
        plr_kernel<<<(m + 3) / 4, 256, 0, stream>>>(cxn + (size_t)s * NFEAT, cxc + (size_t)s * NCAT,
                                                    m, freq, plr_w, plr_b, inC);
        sgemm(inC, lin_w, xC, m, DM, DIN, lin_b, nullptr, 0, 0);
        sgemm(xC, enc_w1, hC, m, DBK, DM, enc_b1, nullptr, 1, 0);
        sgemm(hC, enc_w2, xC, m, DM, DBK, enc_b2, xC, 0, 0);
        float* lnC = inC;                       // inC dead
        ln_kernel<<<(m + 3) / 4, 256, 0, stream>>>(xC, lnC, mix_g, mix_b, m);
        sgemm(lnC, K_w, kC, m, DM, DM, K_b, nullptr, 0, 0);            // kC in hC
        sgemm(kC, T_w1, (float*)(T1c + (size_t)s * DBK), m, DBK, DM,
              nullptr, nullptr, 0, 1);                                  // bf16 out
        cnorm_kernel<<<(m + 3) / 4, 256, 0, stream>>>(kC, cnC, m);
        {
            dim3 grid((m + 127) / 128, (NB + 127) / 128);
            sgemm_nt_kernel<<<grid, 256, 0, stream>>>(kB, kC, scoresC, NB, m, DM, cnC);
        }
        topk_merge_kernel<<<NB, 256, 0, stream>>>(scoresC, m, s, pI, pS, nI, nS);
        { const int* t = pI; pI = nI; nI = (int*)t; }
        { const float* t = pS; pS = nS; nS = (float*)t; }
    }

    // ---------- aggregation + predictor + head ----------
    agg_kernel<<<NB, 256, 0, stream>>>(pI, pS, cand_y, T1b, T1c, T_b1,
                                       xB, label_w, label_b, sbuf, ubuf);
    sgemm(sbuf, T_w2, x2, NB, DM, DBK, nullptr, ubuf, 0, 0);
    ln_kernel<<<(NB + 3) / 4, 256, 0, stream>>>(x2, h2, pred_g, pred_b, NB);
    sgemm(h2, pred_w1, hp, NB, DBK, DM, pred_b1, nullptr, 1, 0);
    sgemm(hp, pred_w2, x3, NB, DM, DBK, pred_b2, x2, 0, 0);
    head_kernel<<<(NB + 3) / 4, 256, 0, stream>>>(x3, head_g, head_b, head_w, head_bias, out, NB);
}

// Round 4
// 3697.134 us; speedup vs baseline: 1.9582x; 1.9582x over previous
//
#include <hip/hip_runtime.h>

#define NCAND 50000
#define NB    512
#define DIN   820
#define KP_IN 832
#define DM    512
#define DBK   1024
#define NFEAT 50
#define NCAT  20
#define NFREQ 16
#define DEMB  16
#define CTX   96

typedef __attribute__((ext_vector_type(8))) short short8;
typedef __attribute__((ext_vector_type(4))) float f32x4;

static __device__ __forceinline__ unsigned short f2bf(float f) {
    union { float f; unsigned int i; } u; u.f = f;
    unsigned int r = u.i + 0x7FFFu + ((u.i >> 16) & 1u);
    return (unsigned short)(r >> 16);
}
static __device__ __forceinline__ float bf2f(unsigned short s) {
    union { unsigned int i; float f; } u; u.i = ((unsigned int)s) << 16;
    return u.f;
}

#define GLDS16(g, l) __builtin_amdgcn_global_load_lds( \
    (const __attribute__((address_space(1))) void*)(g), \
    (__attribute__((address_space(3))) void*)(l), 16, 0, 0)

#define BG_RELU  1
#define BG_SCORE 2

// ---------------------------------------------------------------- weight prep
__global__ __launch_bounds__(256) void wprep_kernel(
    const float* __restrict__ W, int K, int N, int Kp,
    unsigned short* __restrict__ Wh, unsigned short* __restrict__ Wl)
{
    int idx = blockIdx.x * 256 + threadIdx.x;
    if (idx >= N * Kp) return;
    int n = idx / Kp, k = idx % Kp;
    float v = (k < K) ? W[(size_t)k * N + n] : 0.f;
    unsigned short h = f2bf(v);
    Wh[idx] = h;
    if (Wl) Wl[idx] = f2bf(v - bf2f(h));
}

// ---------------------------------------------------------------- PLR encode (bf16 hi/lo out)
__global__ __launch_bounds__(256) void plr_bf16_kernel(
    const float* __restrict__ xn_, const float* __restrict__ xc_, int nrows,
    const float* __restrict__ freq, const float* __restrict__ plr_w,
    const float* __restrict__ plr_b,
    unsigned short* __restrict__ oh, unsigned short* __restrict__ ol)
{
    __shared__ float sW[32 * 16];
    __shared__ float sB[16];
    __shared__ float sF[NFEAT * NFREQ];
    int tid = threadIdx.x;
    for (int i = tid; i < 512; i += 256) sW[i] = plr_w[i];
    if (tid < 16) sB[tid] = plr_b[tid];
    for (int i = tid; i < NFEAT * NFREQ; i += 256) sF[i] = freq[i];
    __syncthreads();
    int wave = tid >> 6, lane = tid & 63;
    int row = blockIdx.x * 4 + wave;
    if (row >= nrows) return;
    const float* xn = xn_ + (size_t)row * NFEAT;
    const float* xc = xc_ + (size_t)row * NCAT;
    unsigned short* ph = oh + (size_t)row * KP_IN;
    unsigned short* pl = ol + (size_t)row * KP_IN;
    if (lane < NFEAT) {
        float x = xn[lane];
        float cs[NFREQ], sn[NFREQ];
        #pragma unroll
        for (int j = 0; j < NFREQ; j++) {
            float p = 6.28318530717958647692f * sF[lane * NFREQ + j] * x;
            sn[j] = __sinf(p);
            cs[j] = __cosf(p);
        }
        #pragma unroll
        for (int d = 0; d < DEMB; d++) {
            float acc = sB[d];
            #pragma unroll
            for (int j = 0; j < NFREQ; j++)
                acc = fmaf(cs[j], sW[j * DEMB + d], fmaf(sn[j], sW[(NFREQ + j) * DEMB + d], acc));
            float v = fmaxf(acc, 0.f);
            unsigned short h = f2bf(v);
            ph[lane * DEMB + d] = h;
            pl[lane * DEMB + d] = f2bf(v - bf2f(h));
        }
    }
    if (lane < NCAT) {
        float v = xc[lane];
        unsigned short h = f2bf(v);
        ph[800 + lane] = h;
        pl[800 + lane] = f2bf(v - bf2f(h));
    }
    if (lane >= NCAT && lane < 32) {
        ph[800 + lane] = 0;
        pl[800 + lane] = 0;
    }
}

// ---------------------------------------------------------------- bf16 MFMA GEMM (plain, 1-term)
__global__ __launch_bounds__(256) void bgemm_kernel(
    const unsigned short* __restrict__ A, const unsigned short* __restrict__ Bt,
    int M, int N, int Kp,
    float* __restrict__ Cf, unsigned short* __restrict__ Cb,
    const float* __restrict__ bias, int flags)
{
    __shared__ unsigned short As[128 * 32];
    __shared__ unsigned short Bs[128 * 32];
    int tid = threadIdx.x;
    int w = tid >> 6, lane = tid & 63;
    int m0 = blockIdx.y * 128, n0 = blockIdx.x * 128;
    int wr = (w >> 1) * 64, wc = (w & 1) * 64;

    f32x4 acc[4][4];
    #pragma unroll
    for (int i = 0; i < 4; i++)
        #pragma unroll
        for (int j = 0; j < 4; j++) acc[i][j] = (f32x4){0.f, 0.f, 0.f, 0.f};

    int srow = w * 32 + (lane >> 2);
    int scol = (lane & 3) * 8;
    const unsigned short* pa0 = A  + (size_t)min(m0 + srow,      M - 1) * Kp + scol;
    const unsigned short* pa1 = A  + (size_t)min(m0 + srow + 16, M - 1) * Kp + scol;
    const unsigned short* pb0 = Bt + (size_t)min(n0 + srow,      N - 1) * Kp + scol;
    const unsigned short* pb1 = Bt + (size_t)min(n0 + srow + 16, N - 1) * Kp + scol;
    unsigned short* la0 = &As[(w * 32) * 32];
    unsigned short* la1 = &As[(w * 32 + 16) * 32];
    unsigned short* lb0 = &Bs[(w * 32) * 32];
    unsigned short* lb1 = &Bs[(w * 32 + 16) * 32];

    int fr = lane & 15, q = lane >> 4;

    for (int k0 = 0; k0 < Kp; k0 += 32) {
        __syncthreads();
        GLDS16(pa0 + k0, la0);
        GLDS16(pa1 + k0, la1);
        GLDS16(pb0 + k0, lb0);
        GLDS16(pb1 + k0, lb1);
        __syncthreads();
        short8 a[4], b[4];
        #pragma unroll
        for (int i = 0; i < 4; i++)
            a[i] = *(const short8*)&As[(wr + i * 16 + fr) * 32 + q * 8];
        #pragma unroll
        for (int j = 0; j < 4; j++)
            b[j] = *(const short8*)&Bs[(wc + j * 16 + fr) * 32 + q * 8];
        #pragma unroll
        for (int i = 0; i < 4; i++)
            #pragma unroll
            for (int j = 0; j < 4; j++)
                acc[i][j] = __builtin_amdgcn_mfma_f32_16x16x32_bf16(a[i], b[j], acc[i][j], 0, 0, 0);
    }

    int col = lane & 15, rq = (lane >> 4) * 4;
    #pragma unroll
    for (int i = 0; i < 4; i++)
        #pragma unroll
        for (int j = 0; j < 4; j++) {
            int n_g = n0 + wc + j * 16 + col;
            #pragma unroll
            for (int r = 0; r < 4; r++) {
                int m_g = m0 + wr + i * 16 + rq + r;
                if (m_g < M && n_g < N) {
                    float v = acc[i][j][r];
                    if (bias) v += bias[n_g];
                    if (flags & BG_RELU) v = fmaxf(v, 0.f);
                    if (Cf) Cf[(size_t)m_g * N + n_g] = v;
                    if (Cb) Cb[(size_t)m_g * N + n_g] = f2bf(v);
                }
            }
        }
}

// ------------------------------------------- bf16 MFMA GEMM, 3-term split (~fp32)
// acc = Ah*Bh + Al*Bh + Ah*Bl
__global__ __launch_bounds__(256) void bgemm3_kernel(
    const unsigned short* __restrict__ Ah, const unsigned short* __restrict__ Al,
    const unsigned short* __restrict__ Bh, const unsigned short* __restrict__ Bl,
    int M, int N, int Kp,
    float* __restrict__ Cf, unsigned short* __restrict__ Cbh, unsigned short* __restrict__ Cbl,
    const float* __restrict__ bias, const float* __restrict__ resf,
    const float* __restrict__ cnorm, int flags)
{
    __shared__ unsigned short Ash[128 * 32];
    __shared__ unsigned short Asl[128 * 32];
    __shared__ unsigned short Bsh[128 * 32];
    __shared__ unsigned short Bsl[128 * 32];
    int tid = threadIdx.x;
    int w = tid >> 6, lane = tid & 63;
    int m0 = blockIdx.y * 128, n0 = blockIdx.x * 128;
    int wr = (w >> 1) * 64, wc = (w & 1) * 64;

    f32x4 acc[4][4];
    #pragma unroll
    for (int i = 0; i < 4; i++)
        #pragma unroll
        for (int j = 0; j < 4; j++) acc[i][j] = (f32x4){0.f, 0.f, 0.f, 0.f};

    int srow = w * 32 + (lane >> 2);
    int scol = (lane & 3) * 8;
    size_t ra0 = (size_t)min(m0 + srow,      M - 1) * Kp + scol;
    size_t ra1 = (size_t)min(m0 + srow + 16, M - 1) * Kp + scol;
    size_t rb0 = (size_t)min(n0 + srow,      N - 1) * Kp + scol;
    size_t rb1 = (size_t)min(n0 + srow + 16, N - 1) * Kp + scol;
    unsigned short* lah0 = &Ash[(w * 32) * 32];
    unsigned short* lah1 = &Ash[(w * 32 + 16) * 32];
    unsigned short* lal0 = &Asl[(w * 32) * 32];
    unsigned short* lal1 = &Asl[(w * 32 + 16) * 32];
    unsigned short* lbh0 = &Bsh[(w * 32) * 32];
    unsigned short* lbh1 = &Bsh[(w * 32 + 16) * 32];
    unsigned short* lbl0 = &Bsl[(w * 32) * 32];
    unsigned short* lbl1 = &Bsl[(w * 32 + 16) * 32];

    int fr = lane & 15, q = lane >> 4;

    for (int k0 = 0; k0 < Kp; k0 += 32) {
        __syncthreads();
        GLDS16(Ah + ra0 + k0, lah0);
        GLDS16(Ah + ra1 + k0, lah1);
        GLDS16(Al + ra0 + k0, lal0);
        GLDS16(Al + ra1 + k0, lal1);
        GLDS16(Bh + rb0 + k0, lbh0);
        GLDS16(Bh + rb1 + k0, lbh1);
        GLDS16(Bl + rb0 + k0, lbl0);
        GLDS16(Bl + rb1 + k0, lbl1);
        __syncthreads();
        short8 a[4], b[4];
        #pragma unroll
        for (int i = 0; i < 4; i++)
            a[i] = *(const short8*)&Ash[(wr + i * 16 + fr) * 32 + q * 8];
        #pragma unroll
        for (int j = 0; j < 4; j++)
            b[j] = *(const short8*)&Bsh[(wc + j * 16 + fr) * 32 + q * 8];
        #pragma unroll
        for (int i = 0; i < 4; i++)
            #pragma unroll
            for (int j = 0; j < 4; j++)
                acc[i][j] = __builtin_amdgcn_mfma_f32_16x16x32_bf16(a[i], b[j], acc[i][j], 0, 0, 0);
        short8 al[4];
        #pragma unroll
        for (int i = 0; i < 4; i++)
            al[i] = *(const short8*)&Asl[(wr + i * 16 + fr) * 32 + q * 8];
        #pragma unroll
        for (int i = 0; i < 4; i++)
            #pragma unroll
            for (int j = 0; j < 4; j++)
                acc[i][j] = __builtin_amdgcn_mfma_f32_16x16x32_bf16(al[i], b[j], acc[i][j], 0, 0, 0);
        short8 bl[4];
        #pragma unroll
        for (int j = 0; j < 4; j++)
            bl[j] = *(const short8*)&Bsl[(wc + j * 16 + fr) * 32 + q * 8];
        #pragma unroll
        for (int i = 0; i < 4; i++)
            #pragma unroll
            for (int j = 0; j < 4; j++)
                acc[i][j] = __builtin_amdgcn_mfma_f32_16x16x32_bf16(a[i], bl[j], acc[i][j], 0, 0, 0);
    }

    int col = lane & 15, rq = (lane >> 4) * 4;
    #pragma unroll
    for (int i = 0; i < 4; i++)
        #pragma unroll
        for (int j = 0; j < 4; j++) {
            int n_g = n0 + wc + j * 16 + col;
            #pragma unroll
            for (int r = 0; r < 4; r++) {
                int m_g = m0 + wr + i * 16 + rq + r;
                if (m_g < M && n_g < N) {
                    float v = acc[i][j][r];
                    if (bias) v += bias[n_g];
                    if (resf) v += resf[(size_t)m_g * N + n_g];
                    if (flags & BG_RELU) v = fmaxf(v, 0.f);
                    if (flags & BG_SCORE) v = 2.f * v - cnorm[n_g];
                    if (Cf) Cf[(size_t)m_g * N + n_g] = v;
                    if (Cbh) {
                        unsigned short h = f2bf(v);
                        Cbh[(size_t)m_g * N + n_g] = h;
                        if (Cbl) Cbl[(size_t)m_g * N + n_g] = f2bf(v - bf2f(h));
                    }
                }
            }
        }
}

// ------------------------------------------------- fp32 GEMM (predictor tail only)
__global__ __launch_bounds__(256) void sgemm_kernel(
    const float* __restrict__ A, const float* __restrict__ W,
    float* C, int M, int N, int K,
    const float* __restrict__ bias, const float* res, int do_relu)
{
    __shared__ float As[8][132];
    __shared__ float Ws[8][132];
    int tid = threadIdx.x;
    int bm = blockIdx.y * 128;
    int bn = blockIdx.x * 128;
    int tx = tid & 15, ty = tid >> 4;
    float acc[8][8];
    #pragma unroll
    for (int i = 0; i < 8; i++)
        #pragma unroll
        for (int j = 0; j < 8; j++) acc[i][j] = 0.f;

    int a_row = tid >> 1;
    int a_k4  = (tid & 1) * 4;
    int w_k   = tid >> 5;
    int w_n   = (tid & 31) * 4;

    for (int k0 = 0; k0 < K; k0 += 8) {
        float4 av = make_float4(0.f, 0.f, 0.f, 0.f);
        {
            int gm = bm + a_row, gk = k0 + a_k4;
            if (gm < M) {
                const float* p = A + (size_t)gm * K;
                if (gk + 4 <= K) av = *(const float4*)(p + gk);
                else {
                    if (gk + 0 < K) av.x = p[gk + 0];
                    if (gk + 1 < K) av.y = p[gk + 1];
                    if (gk + 2 < K) av.z = p[gk + 2];
                    if (gk + 3 < K) av.w = p[gk + 3];
                }
            }
        }
        float4 wv = make_float4(0.f, 0.f, 0.f, 0.f);
        {
            int gk = k0 + w_k, gn = bn + w_n;
            if (gk < K) wv = *(const float4*)(W + (size_t)gk * N + gn);
        }
        __syncthreads();
        As[a_k4 + 0][a_row] = av.x;
        As[a_k4 + 1][a_row] = av.y;
        As[a_k4 + 2][a_row] = av.z;
        As[a_k4 + 3][a_row] = av.w;
        *(float4*)&Ws[w_k][w_n] = wv;
        __syncthreads();
        #pragma unroll
        for (int kk = 0; kk < 8; kk++) {
            float4 a0 = *(const float4*)&As[kk][ty * 4];
            float4 a1 = *(const float4*)&As[kk][64 + ty * 4];
            float4 b0 = *(const float4*)&Ws[kk][tx * 4];
            float4 b1 = *(const float4*)&Ws[kk][64 + tx * 4];
            float aa[8] = {a0.x, a0.y, a0.z, a0.w, a1.x, a1.y, a1.z, a1.w};
            float bb[8] = {b0.x, b0.y, b0.z, b0.w, b1.x, b1.y, b1.z, b1.w};
            #pragma unroll
            for (int i = 0; i < 8; i++)
                #pragma unroll
                for (int j = 0; j < 8; j++)
                    acc[i][j] = fmaf(aa[i], bb[j], acc[i][j]);
        }
    }
    #pragma unroll
    for (int ih = 0; ih < 2; ih++)
    #pragma unroll
    for (int ii = 0; ii < 4; ii++) {
        int m = bm + ih * 64 + ty * 4 + ii;
        if (m >= M) continue;
        #pragma unroll
        for (int jh = 0; jh < 2; jh++) {
            int n = bn + jh * 64 + tx * 4;
            float v0 = acc[ih * 4 + ii][jh * 4 + 0];
            float v1 = acc[ih * 4 + ii][jh * 4 + 1];
            float v2 = acc[ih * 4 + ii][jh * 4 + 2];
            float v3 = acc[ih * 4 + ii][jh * 4 + 3];
            if (bias) { v0 += bias[n]; v1 += bias[n + 1]; v2 += bias[n + 2]; v3 += bias[n + 3]; }
            if (res) {
                const float* r = res + (size_t)m * N + n;
                v0 += r[0]; v1 += r[1]; v2 += r[2]; v3 += r[3];
            }
            if (do_relu) {
                v0 = fmaxf(v0, 0.f); v1 = fmaxf(v1, 0.f);
                v2 = fmaxf(v2, 0.f); v3 = fmaxf(v3, 0.f);
            }
            *(float4*)(C + (size_t)m * N + n) = make_float4(v0, v1, v2, v3);
        }
    }
}

// ---------------------------------------------------------------- LayerNorm fp32 out
__global__ __launch_bounds__(256) void ln_kernel(const float* __restrict__ X,
    float* __restrict__ Y, const float* __restrict__ g, const float* __restrict__ bt, int M)
{
    int wave = threadIdx.x >> 6, lane = threadIdx.x & 63;
    int row = blockIdx.x * 4 + wave;
    if (row >= M) return;
    const float* x = X + (size_t)row * DM;
    float4 v0 = ((const float4*)x)[lane * 2];
    float4 v1 = ((const float4*)x)[lane * 2 + 1];
    float s = v0.x + v0.y + v0.z + v0.w + v1.x + v1.y + v1.z + v1.w;
    #pragma unroll
    for (int off = 32; off; off >>= 1) s += __shfl_xor(s, off, 64);
    float m = s * (1.f / DM);
    float q = (v0.x - m) * (v0.x - m) + (v0.y - m) * (v0.y - m)
            + (v0.z - m) * (v0.z - m) + (v0.w - m) * (v0.w - m)
            + (v1.x - m) * (v1.x - m) + (v1.y - m) * (v1.y - m)
            + (v1.z - m) * (v1.z - m) + (v1.w - m) * (v1.w - m);
    #pragma unroll
    for (int off = 32; off; off >>= 1) q += __shfl_xor(q, off, 64);
    float rstd = 1.f / sqrtf(q * (1.f / DM) + 1e-5f);
    float4 g0 = ((const float4*)g)[lane * 2], g1 = ((const float4*)g)[lane * 2 + 1];
    float4 b0 = ((const float4*)bt)[lane * 2], b1 = ((const float4*)bt)[lane * 2 + 1];
    float4 y0 = make_float4((v0.x - m) * rstd * g0.x + b0.x, (v0.y - m) * rstd * g0.y + b0.y,
                            (v0.z - m) * rstd * g0.z + b0.z, (v0.w - m) * rstd * g0.w + b0.w);
    float4 y1 = make_float4((v1.x - m) * rstd * g1.x + b1.x, (v1.y - m) * rstd * g1.y + b1.y,
                            (v1.z - m) * rstd * g1.z + b1.z, (v1.w - m) * rstd * g1.w + b1.w);
    float* y = Y + (size_t)row * DM;
    ((float4*)y)[lane * 2] = y0;
    ((float4*)y)[lane * 2 + 1] = y1;
}

// ---------------------------------------------------------------- LayerNorm bf16 hi/lo out
__global__ __launch_bounds__(256) void ln_split_kernel(const float* __restrict__ X,
    unsigned short* __restrict__ Yh, unsigned short* __restrict__ Yl,
    const float* __restrict__ g, const float* __restrict__ bt, int M)
{
    int wave = threadIdx.x >> 6, lane = threadIdx.x & 63;
    int row = blockIdx.x * 4 + wave;
    if (row >= M) return;
    const float* x = X + (size_t)row * DM;
    float4 v0 = ((const float4*)x)[lane * 2];
    float4 v1 = ((const float4*)x)[lane * 2 + 1];
    float s = v0.x + v0.y + v0.z + v0.w + v1.x + v1.y + v1.z + v1.w;
    #pragma unroll
    for (int off = 32; off; off >>= 1) s += __shfl_xor(s, off, 64);
    float m = s * (1.f / DM);
    float q = (v0.x - m) * (v0.x - m) + (v0.y - m) * (v0.y - m)
            + (v0.z - m) * (v0.z - m) + (v0.w - m) * (v0.w - m)
            + (v1.x - m) * (v1.x - m) + (v1.y - m) * (v1.y - m)
            + (v1.z - m) * (v1.z - m) + (v1.w - m) * (v1.w - m);
    #pragma unroll
    for (int off = 32; off; off >>= 1) q += __shfl_xor(q, off, 64);
    float rstd = 1.f / sqrtf(q * (1.f / DM) + 1e-5f);
    float vals[8] = {v0.x, v0.y, v0.z, v0.w, v1.x, v1.y, v1.z, v1.w};
    unsigned short* yh = Yh + (size_t)row * DM + lane * 8;
    unsigned short* yl = Yl + (size_t)row * DM + lane * 8;
    const float* gp = g + lane * 8;
    const float* bp = bt + lane * 8;
    #pragma unroll
    for (int i = 0; i < 8; i++) {
        float y = (vals[i] - m) * rstd * gp[i] + bp[i];
        unsigned short h = f2bf(y);
        yh[i] = h;
        yl[i] = f2bf(y - bf2f(h));
    }
}

// ---------------------------------------------------------------- key norms (fp32 k)
__global__ __launch_bounds__(256) void cnorm_kernel(const float* __restrict__ Kc,
    float* __restrict__ cn, int N)
{
    int wave = threadIdx.x >> 6, lane = threadIdx.x & 63;
    int row = blockIdx.x * 4 + wave;
    if (row >= N) return;
    const float* x = Kc + (size_t)row * DM;
    float4 v0 = ((const float4*)x)[lane * 2];
    float4 v1 = ((const float4*)x)[lane * 2 + 1];
    float s = v0.x * v0.x + v0.y * v0.y + v0.z * v0.z + v0.w * v0.w
            + v1.x * v1.x + v1.y * v1.y + v1.z * v1.z + v1.w * v1.w;
    #pragma unroll
    for (int off = 32; off; off >>= 1) s += __shfl_xor(s, off, 64);
    if (lane == 0) cn[row] = s;
}

// ---------------------------------------------------------------- ctx init
__global__ void ctx_init_kernel(int* __restrict__ idx, float* __restrict__ sc)
{
    int i = blockIdx.x * 256 + threadIdx.x;
    if (i < NB * CTX) { idx[i] = 0; sc[i] = -1e30f; }
}

// ------------------------------------- running top-96 merge
#define NBINS 4096
#define CANDCAP 2048
__global__ __launch_bounds__(256) void topk_merge_kernel(
    const float* __restrict__ S, int m, int base,
    const int* __restrict__ pidx, const float* __restrict__ pscore,
    int* __restrict__ nidx, float* __restrict__ nscore)
{
    __shared__ int   hist[NBINS];
    __shared__ float red[256];
    __shared__ float prev_s[CTX];
    __shared__ int   prev_i[CTX];
    __shared__ float s_mn, s_scale;
    __shared__ int   s_bstar, s_m, nsel, ncnd;
    __shared__ float cnd_s[CANDCAP];
    __shared__ int   cnd_g[CANDCAP];
    __shared__ float sel_s[CTX];
    __shared__ int   sel_g[CTX];

    int b = blockIdx.x, tid = threadIdx.x;
    const float* Sb = S + (size_t)b * m;
    if (tid < CTX) { prev_s[tid] = pscore[b * CTX + tid]; prev_i[tid] = pidx[b * CTX + tid]; }
    for (int i = tid; i < NBINS; i += 256) hist[i] = 0;
    __syncthreads();
    int tot = m + CTX;
    float mn = 1e30f, mx = -1e30f;
    for (int i = tid; i < tot; i += 256) {
        float v = (i < m) ? Sb[i] : prev_s[i - m];
        if (v > -1e29f) { mn = fminf(mn, v); mx = fmaxf(mx, v); }
    }
    red[tid] = mx; __syncthreads();
    for (int s = 128; s > 0; s >>= 1) { if (tid < s) red[tid] = fmaxf(red[tid], red[tid + s]); __syncthreads(); }
    float gmx = red[0]; __syncthreads();
    red[tid] = mn; __syncthreads();
    for (int s = 128; s > 0; s >>= 1) { if (tid < s) red[tid] = fminf(red[tid], red[tid + s]); __syncthreads(); }
    float gmn = red[0]; __syncthreads();
    if (tid == 0) {
        float w = gmx - gmn;
        if (!(w > 0.f)) w = 1.f;
        s_mn = gmn;
        s_scale = (float)NBINS / w * 0.9999990f;
        nsel = 0; ncnd = 0;
    }
    __syncthreads();
    float lmn = s_mn, lsc = s_scale;
    for (int i = tid; i < tot; i += 256) {
        float v = (i < m) ? Sb[i] : prev_s[i - m];
        if (v <= -1e29f) continue;
        int bin = (int)((v - lmn) * lsc);
        bin = max(0, min(NBINS - 1, bin));
        atomicAdd(&hist[bin], 1);
    }
    __syncthreads();
    if (tid == 0) {
        int cum = 0, bb = 0;
        for (int i = NBINS - 1; i >= 0; i--) {
            int h = hist[i];
            if (cum + h >= CTX) { bb = i; break; }
            cum += h;
        }
        s_bstar = bb; s_m = CTX - cum;
    }
    __syncthreads();
    int bstar = s_bstar;
    for (int i = tid; i < tot; i += 256) {
        float v = (i < m) ? Sb[i] : prev_s[i - m];
        if (v <= -1e29f) continue;
        int g = (i < m) ? (base + i) : prev_i[i - m];
        int bin = (int)((v - lmn) * lsc);
        bin = max(0, min(NBINS - 1, bin));
        if (bin > bstar) {
            int p = atomicAdd(&nsel, 1);
            sel_s[p] = v; sel_g[p] = g;
        } else if (bin == bstar) {
            int p = atomicAdd(&ncnd, 1);
            if (p < CANDCAP) { cnd_s[p] = v; cnd_g[p] = g; }
        }
    }
    __syncthreads();
    int msel = s_m;
    int nc = min(ncnd, CANDCAP);
    for (int i = tid; i < nc; i += 256) {
        float si = cnd_s[i]; int gi = cnd_g[i];
        int rank = 0;
        for (int j = 0; j < nc; j++) {
            float sj = cnd_s[j];
            rank += (sj > si) || (sj == si && cnd_g[j] < gi);
        }
        if (rank < msel) {
            int p = atomicAdd(&nsel, 1);
            sel_s[p] = si; sel_g[p] = gi;
        }
    }
    __syncthreads();
    if (tid < CTX) {
        nidx[b * CTX + tid] = sel_g[tid];
        nscore[b * CTX + tid] = sel_s[tid];
    }
}

// ------------------------------- softmax + label/value context aggregation
__global__ __launch_bounds__(256) void agg_kernel(
    const int* __restrict__ ctx_idx, const float* __restrict__ ctx_score,
    const float* __restrict__ cand_y, const float* __restrict__ T1b,
    const unsigned short* __restrict__ T1c, const float* __restrict__ T_b1,
    const float* __restrict__ x_batch,
    const float* __restrict__ label_w, const float* __restrict__ label_b,
    float* __restrict__ s_out, float* __restrict__ u_out)
{
    __shared__ float p_s[CTX];
    __shared__ int   p_i[CTX];
    __shared__ float s_ybar;
    int b = blockIdx.x, tid = threadIdx.x;
    if (tid < CTX) { p_s[tid] = ctx_score[b * CTX + tid]; p_i[tid] = ctx_idx[b * CTX + tid]; }
    __syncthreads();
    if (tid == 0) {
        float mx = -1e30f;
        for (int c = 0; c < CTX; c++) mx = fmaxf(mx, p_s[c]);
        float sum = 0.f;
        for (int c = 0; c < CTX; c++) { float e = __expf(p_s[c] - mx); p_s[c] = e; sum += e; }
        float inv = 1.f / sum, yb = 0.f;
        for (int c = 0; c < CTX; c++) { p_s[c] *= inv; yb += p_s[c] * cand_y[p_i[c]]; }
        s_ybar = yb;
    }
    __syncthreads();
    int j = tid * 4;
    float4 kv = *(const float4*)(T1b + (size_t)b * DBK + j);
    float4 tb = *(const float4*)(T_b1 + j);
    float base0 = kv.x + tb.x, base1 = kv.y + tb.y, base2 = kv.z + tb.z, base3 = kv.w + tb.w;
    float a0 = 0.f, a1 = 0.f, a2 = 0.f, a3 = 0.f;
    for (int c = 0; c < CTX; c++) {
        float p = p_s[c];
        ushort4 cu = *(const ushort4*)(T1c + (size_t)p_i[c] * DBK + j);
        a0 = fmaf(p, fmaxf(base0 - bf2f(cu.x), 0.f), a0);
        a1 = fmaf(p, fmaxf(base1 - bf2f(cu.y), 0.f), a1);
        a2 = fmaf(p, fmaxf(base2 - bf2f(cu.z), 0.f), a2);
        a3 = fmaf(p, fmaxf(base3 - bf2f(cu.w), 0.f), a3);
    }
    *(float4*)(s_out + (size_t)b * DBK + j) = make_float4(a0, a1, a2, a3);
    if (tid < 128) {
        int d = tid * 4;
        float4 xv = *(const float4*)(x_batch + (size_t)b * DM + d);
        float4 lw = *(const float4*)(label_w + d);
        float4 lb = *(const float4*)(label_b + d);
        float yb = s_ybar;
        *(float4*)(u_out + (size_t)b * DM + d) =
            make_float4(xv.x + yb * lw.x + lb.x, xv.y + yb * lw.y + lb.y,
                        xv.z + yb * lw.z + lb.z, xv.w + yb * lw.w + lb.w);
    }
}

// ---------------------------------------------------------------- head
__global__ __launch_bounds__(256) void head_kernel(
    const float* __restrict__ X, const float* __restrict__ g,
    const float* __restrict__ bt, const float* __restrict__ w,
    const float* __restrict__ hb, float* __restrict__ out, int M)
{
    int wave = threadIdx.x >> 6, lane = threadIdx.x & 63;
    int row = blockIdx.x * 4 + wave;
    if (row >= M) return;
    const float* x = X + (size_t)row * DM;
    float4 v0 = ((const float4*)x)[lane * 2];
    float4 v1 = ((const float4*)x)[lane * 2 + 1];
    float s = v0.x + v0.y + v0.z + v0.w + v1.x + v1.y + v1.z + v1.w;
    #pragma unroll
    for (int off = 32; off; off >>= 1) s += __shfl_xor(s, off, 64);
    float m = s * (1.f / DM);
    float q = (v0.x - m) * (v0.x - m) + (v0.y - m) * (v0.y - m)
            + (v0.z - m) * (v0.z - m) + (v0.w - m) * (v0.w - m)
            + (v1.x - m) * (v1.x - m) + (v1.y - m) * (v1.y - m)
            + (v1.z - m) * (v1.z - m) + (v1.w - m) * (v1.w - m);
    #pragma unroll
    for (int off = 32; off; off >>= 1) q += __shfl_xor(q, off, 64);
    float rstd = 1.f / sqrtf(q * (1.f / DM) + 1e-5f);
    float4 g0 = ((const float4*)g)[lane * 2], g1 = ((const float4*)g)[lane * 2 + 1];
    float4 b0 = ((const float4*)bt)[lane * 2], b1 = ((const float4*)bt)[lane * 2 + 1];
    float4 w0 = ((const float4*)w)[lane * 2], w1 = ((const float4*)w)[lane * 2 + 1];
    float t = 0.f;
    t += fmaxf((v0.x - m) * rstd * g0.x + b0.x, 0.f) * w0.x;
    t += fmaxf((v0.y - m) * rstd * g0.y + b0.y, 0.f) * w0.y;
    t += fmaxf((v0.z - m) * rstd * g0.z + b0.z, 0.f) * w0.z;
    t += fmaxf((v0.w - m) * rstd * g0.w + b0.w, 0.f) * w0.w;
    t += fmaxf((v1.x - m) * rstd * g1.x + b1.x, 0.f) * w1.x;
    t += fmaxf((v1.y - m) * rstd * g1.y + b1.y, 0.f) * w1.y;
    t += fmaxf((v1.z - m) * rstd * g1.z + b1.z, 0.f) * w1.z;
    t += fmaxf((v1.w - m) * rstd * g1.w + b1.w, 0.f) * w1.w;
    #pragma unroll
    for (int off = 32; off; off >>= 1) t += __shfl_xor(t, off, 64);
    if (lane == 0) out[row] = t + hb[0];
}

// =================================================================== host
extern "C" void kernel_launch(void* const* d_in, const int* in_sizes, int n_in,
                              void* d_out, int out_size, void* d_ws, size_t ws_size,
                              hipStream_t stream) {
    (void)in_sizes; (void)n_in; (void)out_size;
    const float* x_num   = (const float*)d_in[0];
    const float* x_cat   = (const float*)d_in[1];
    const float* cxn     = (const float*)d_in[2];
    const float* cxc     = (const float*)d_in[3];
    const float* cand_y  = (const float*)d_in[4];
    const float* freq    = (const float*)d_in[6];
    const float* plr_w   = (const float*)d_in[7];
    const float* plr_b   = (const float*)d_in[8];
    const float* lin_w   = (const float*)d_in[9];
    const float* lin_b   = (const float*)d_in[10];
    const float* enc_w1  = (const float*)d_in[11];
    const float* enc_b1  = (const float*)d_in[12];
    const float* enc_w2  = (const float*)d_in[13];
    const float* enc_b2  = (const float*)d_in[14];
    const float* mix_g   = (const float*)d_in[15];
    const float* mix_b   = (const float*)d_in[16];
    const float* K_w     = (const float*)d_in[17];
    const float* K_b     = (const float*)d_in[18];
    const float* label_w = (const float*)d_in[19];
    const float* label_b = (const float*)d_in[20];
    const float* T_w1    = (const float*)d_in[21];
    const float* T_b1    = (const float*)d_in[22];
    const float* T_w2    = (const float*)d_in[23];
    const float* pred_g  = (const float*)d_in[24];
    const float* pred_b  = (const float*)d_in[25];
    const float* pred_w1 = (const float*)d_in[26];
    const float* pred_b1 = (const float*)d_in[27];
    const float* pred_w2 = (const float*)d_in[28];
    const float* pred_b2 = (const float*)d_in[29];
    const float* head_g  = (const float*)d_in[30];
    const float* head_b  = (const float*)d_in[31];
    const float* head_w  = (const float*)d_in[32];
    const float* head_bias = (const float*)d_in[33];
    float* out = (float*)d_out;

    char* ws = (char*)d_ws;
    size_t off = 0;
    auto alloc = [&](size_t n) { char* p = ws + off; off = (off + n + 255) & ~(size_t)255; return p; };

    typedef unsigned short u16;
    // --- bf16 weights (transposed to N x Kp), hi/lo ---
    u16* lin_wt_h = (u16*)alloc((size_t)DM * KP_IN * 2);
    u16* lin_wt_l = (u16*)alloc((size_t)DM * KP_IN * 2);
    u16* e1t_h    = (u16*)alloc((size_t)DBK * DM * 2);
    u16* e1t_l    = (u16*)alloc((size_t)DBK * DM * 2);
    u16* e2t_h    = (u16*)alloc((size_t)DM * DBK * 2);
    u16* e2t_l    = (u16*)alloc((size_t)DM * DBK * 2);
    u16* K_wt_h   = (u16*)alloc((size_t)DM * DM * 2);
    u16* K_wt_l   = (u16*)alloc((size_t)DM * DM * 2);
    u16* T_w1t    = (u16*)alloc((size_t)DBK * DM * 2);
    // --- persistent ---
    u16*   T1c  = (u16*)alloc((size_t)NCAND * DBK * 2);   // 102.4 MB
    float* T1b  = (float*)alloc((size_t)NB * DBK * 4);
    float* xB   = (float*)alloc((size_t)NB * DM * 4);
    u16*   kBh  = (u16*)alloc((size_t)NB * DM * 2);
    u16*   kBl  = (u16*)alloc((size_t)NB * DM * 2);
    // batch scratch
    u16* binh = (u16*)alloc((size_t)NB * KP_IN * 2);
    u16* binl = (u16*)alloc((size_t)NB * KP_IN * 2);
    u16* xBhh = (u16*)alloc((size_t)NB * DM * 2);
    u16* xBhl = (u16*)alloc((size_t)NB * DM * 2);
    u16* hBh  = (u16*)alloc((size_t)NB * DBK * 2);
    u16* hBl  = (u16*)alloc((size_t)NB * DBK * 2);
    u16* lnBh = (u16*)alloc((size_t)NB * DM * 2);
    u16* lnBl = (u16*)alloc((size_t)NB * DM * 2);
    // ctx + predictor
    int*   ctxAi = (int*)alloc((size_t)NB * CTX * 4);
    float* ctxAs = (float*)alloc((size_t)NB * CTX * 4);
    int*   ctxBi = (int*)alloc((size_t)NB * CTX * 4);
    float* ctxBs = (float*)alloc((size_t)NB * CTX * 4);
    float* sbuf = (float*)alloc((size_t)NB * DBK * 4);
    float* ubuf = (float*)alloc((size_t)NB * DM * 4);
    float* x2   = (float*)alloc((size_t)NB * DM * 4);
    float* h2   = (float*)alloc((size_t)NB * DM * 4);
    float* hp   = (float*)alloc((size_t)NB * DBK * 4);
    float* x3   = (float*)alloc((size_t)NB * DM * 4);

    // --- chunk arena ---
    size_t remain = (ws_size > off + 8192) ? (ws_size - off - 8192) : 0;
    const size_t perrow = (size_t)KP_IN * 4      // inCh+inCl
                        + (size_t)DM * 4         // xC fp32
                        + (size_t)DM * 4         // xCh+xCl
                        + (size_t)DBK * 4        // hCh+hCl
                        + (size_t)DM * 4         // lnCh+lnCl
                        + (size_t)DM * 4         // kC fp32
                        + (size_t)DM * 4         // kCh+kCl
                        + 8;                     // cnC + slack
    long ncl = (long)(remain / perrow);
    int NC = (int)(ncl > 6400 ? 6400 : ncl);
    NC &= ~127;
    if (NC < 256) NC = 256;
    u16* inCh = (u16*)alloc((size_t)NC * KP_IN * 2);
    u16* inCl = (u16*)alloc((size_t)NC * KP_IN * 2);
    float* xC = (float*)alloc((size_t)NC * DM * 4);
    u16* xCh  = (u16*)alloc((size_t)NC * DM * 2);
    u16* xCl  = (u16*)alloc((size_t)NC * DM * 2);
    u16* hCh  = (u16*)alloc((size_t)NC * DBK * 2);
    u16* hCl  = (u16*)alloc((size_t)NC * DBK * 2);
    u16* lnCh = (u16*)alloc((size_t)NC * DM * 2);
    u16* lnCl = (u16*)alloc((size_t)NC * DM * 2);
    float* kC = (float*)alloc((size_t)NC * DM * 4);
    u16* kCh  = (u16*)alloc((size_t)NC * DM * 2);
    u16* kCl  = (u16*)alloc((size_t)NC * DM * 2);
    float* cnC = (float*)alloc((size_t)NC * 4);
    // scoresC (NB x NC fp32 = 2048*NC bytes) aliases inCh+inCl (3328*NC bytes, contiguous)
    float* scoresC = (float*)inCh;

    auto bgemm = [&](const u16* A, const u16* Bt, int M, int N, int Kp,
                     float* Cf, u16* Cb, const float* bias, int flags) {
        dim3 grid((N + 127) / 128, (M + 127) / 128);
        bgemm_kernel<<<grid, 256, 0, stream>>>(A, Bt, M, N, Kp, Cf, Cb, bias, flags);
    };
    auto bgemm3 = [&](const u16* Ah, const u16* Al, const u16* Bh, const u16* Bl,
                      int M, int N, int Kp, float* Cf, u16* Cbh, u16* Cbl,
                      const float* bias, const float* resf, const float* cnorm, int flags) {
        dim3 grid((N + 127) / 128, (M + 127) / 128);
        bgemm3_kernel<<<grid, 256, 0, stream>>>(Ah, Al, Bh, Bl, M, N, Kp,
                                                Cf, Cbh, Cbl, bias, resf, cnorm, flags);
    };
    auto sgemm = [&](const float* A, const float* W, float* C, int M, int N, int K,
                     const float* bias, const float* res, int relu) {
        dim3 grid((N + 127) / 128, (M + 127) / 128);
        sgemm_kernel<<<grid, 256, 0, stream>>>(A, W, C, M, N, K, bias, res, relu);
    };
    auto wprep = [&](const float* W, int K, int N, int Kp, u16* Wh, u16* Wl) {
        int n = N * Kp;
        wprep_kernel<<<(n + 255) / 256, 256, 0, stream>>>(W, K, N, Kp, Wh, Wl);
    };

    // ---------- weight prep ----------
    wprep(lin_w, DIN, DM, KP_IN, lin_wt_h, lin_wt_l);
    wprep(enc_w1, DM, DBK, DM, e1t_h, e1t_l);
    wprep(enc_w2, DBK, DM, DBK, e2t_h, e2t_l);
    wprep(K_w, DM, DM, DM, K_wt_h, K_wt_l);
    wprep(T_w1, DM, DBK, DM, T_w1t, nullptr);

    // ---------- batch encode (all split) ----------
    plr_bf16_kernel<<<(NB + 3) / 4, 256, 0, stream>>>(x_num, x_cat, NB, freq, plr_w, plr_b, binh, binl);
    bgemm3(binh, binl, lin_wt_h, lin_wt_l, NB, DM, KP_IN, xB, xBhh, xBhl, lin_b, nullptr, nullptr, 0);
    bgemm3(xBhh, xBhl, e1t_h, e1t_l, NB, DBK, DM, nullptr, hBh, hBl, enc_b1, nullptr, nullptr, BG_RELU);
    bgemm3(hBh, hBl, e2t_h, e2t_l, NB, DM, DBK, xB, nullptr, nullptr, enc_b2, xB, nullptr, 0);
    ln_split_kernel<<<(NB + 3) / 4, 256, 0, stream>>>(xB, lnBh, lnBl, mix_g, mix_b, NB);
    bgemm3(lnBh, lnBl, K_wt_h, K_wt_l, NB, DM, DM, nullptr, kBh, kBl, K_b, nullptr, nullptr, 0);
    bgemm(kBh, T_w1t, NB, DBK, DM, T1b, nullptr, nullptr, 0);
    ctx_init_kernel<<<(NB * CTX + 255) / 256, 256, 0, stream>>>(ctxAi, ctxAs);

    // ---------- candidate chunks ----------
    const int* pI = ctxAi; const float* pS = ctxAs;
    int* nI = ctxBi; float* nS = ctxBs;
    int nch = (NCAND + NC - 1) / NC;
    for (int c = 0; c < nch; c++) {
        int s = c * NC;
        int m = NCAND - s; if (m > NC) m = NC;
        plr_bf16_kernel<<<(m + 3) / 4, 256, 0, stream>>>(cxn + (size_t)s * NFEAT,
                                                         cxc + (size_t)s * NCAT,
                                                         m, freq, plr_w, plr_b, inCh, inCl);
        bgemm3(inCh, inCl, lin_wt_h, lin_wt_l, m, DM, KP_IN, xC, xCh, xCl, lin_b, nullptr, nullptr, 0);
        bgemm3(xCh, xCl, e1t_h, e1t_l, m, DBK, DM, nullptr, hCh, hCl, enc_b1, nullptr, nullptr, BG_RELU);
        bgemm3(hCh, hCl, e2t_h, e2t_l, m, DM, DBK, xC, nullptr, nullptr, enc_b2, xC, nullptr, 0);
        ln_split_kernel<<<(m + 3) / 4, 256, 0, stream>>>(xC, lnCh, lnCl, mix_g, mix_b, m);
        bgemm3(lnCh, lnCl, K_wt_h, K_wt_l, m, DM, DM, kC, kCh, kCl, K_b, nullptr, nullptr, 0);
        cnorm_kernel<<<(m + 3) / 4, 256, 0, stream>>>(kC, cnC, m);
        bgemm(kCh, T_w1t, m, DBK, DM, nullptr, T1c + (size_t)s * DBK, nullptr, 0);
        // scoresC overwrites inCh/inCl — both dead after lin GEMM above
        bgemm3(kBh, kBl, kCh, kCl, NB, m, DM, scoresC, nullptr, nullptr,
               nullptr, nullptr, cnC, BG_SCORE);
        topk_merge_kernel<<<NB, 256, 0, stream>>>(scoresC, m, s, pI, pS, nI, nS);
        { const int* t = pI; pI = nI; nI = (int*)t; }
        { const float* t = pS; pS = nS; nS = (float*)t; }
    }

    // ---------- aggregation + predictor + head (fp32) ----------
    agg_kernel<<<NB, 256, 0, stream>>>(pI, pS, cand_y, T1b, T1c, T_b1,
                                       xB, label_w, label_b, sbuf, ubuf);
    sgemm(sbuf, T_w2, x2, NB, DM, DBK, nullptr, ubuf, 0);
    ln_kernel<<<(NB + 3) / 4, 256, 0, stream>>>(x2, h2, pred_g, pred_b, NB);
    sgemm(h2, pred_w1, hp, NB, DBK, DM, pred_b1, nullptr, 1);
    sgemm(hp, pred_w2, x3, NB, DM, DBK, pred_b2, x2, 0);
    head_kernel<<<(NB + 3) / 4, 256, 0, stream>>>(x3, head_g, head_b, head_w, head_bias, out, NB);
}

// Round 5
// 2939.875 us; speedup vs baseline: 2.4626x; 1.2576x over previous
//
#include <hip/hip_runtime.h>

#define NCAND 50000
#define NB    512
#define DIN   820
#define KP_IN 832
#define DM    512
#define DBK   1024
#define NFEAT 50
#define NCAT  20
#define NFREQ 16
#define DEMB  16
#define CTX   96

typedef __attribute__((ext_vector_type(8))) short short8;
typedef __attribute__((ext_vector_type(4))) float f32x4;

static __device__ __forceinline__ unsigned short f2bf(float f) {
    union { float f; unsigned int i; } u; u.f = f;
    unsigned int r = u.i + 0x7FFFu + ((u.i >> 16) & 1u);
    return (unsigned short)(r >> 16);
}
static __device__ __forceinline__ float bf2f(unsigned short s) {
    union { unsigned int i; float f; } u; u.i = ((unsigned int)s) << 16;
    return u.f;
}

#define GLDS16(g, l) __builtin_amdgcn_global_load_lds( \
    (const __attribute__((address_space(1))) void*)(g), \
    (__attribute__((address_space(3))) void*)(l), 16, 0, 0)

#define BG_RELU  1
#define BG_SCORE 2

// ---------------------------------------------------------------- weight prep
__global__ __launch_bounds__(256) void wprep_kernel(
    const float* __restrict__ W, int K, int N, int Kp,
    unsigned short* __restrict__ Wh, unsigned short* __restrict__ Wl)
{
    int idx = blockIdx.x * 256 + threadIdx.x;
    if (idx >= N * Kp) return;
    int n = idx / Kp, k = idx % Kp;
    float v = (k < K) ? W[(size_t)k * N + n] : 0.f;
    unsigned short h = f2bf(v);
    Wh[idx] = h;
    if (Wl) Wl[idx] = f2bf(v - bf2f(h));
}

// ---------------------------------------------------------------- PLR encode (bf16 hi/lo out)
__global__ __launch_bounds__(256) void plr_bf16_kernel(
    const float* __restrict__ xn_, const float* __restrict__ xc_, int nrows,
    const float* __restrict__ freq, const float* __restrict__ plr_w,
    const float* __restrict__ plr_b,
    unsigned short* __restrict__ oh, unsigned short* __restrict__ ol)
{
    __shared__ float sW[32 * 16];
    __shared__ float sB[16];
    __shared__ float sF[NFEAT * NFREQ];
    int tid = threadIdx.x;
    for (int i = tid; i < 512; i += 256) sW[i] = plr_w[i];
    if (tid < 16) sB[tid] = plr_b[tid];
    for (int i = tid; i < NFEAT * NFREQ; i += 256) sF[i] = freq[i];
    __syncthreads();
    int wave = tid >> 6, lane = tid & 63;
    int row = blockIdx.x * 4 + wave;
    if (row >= nrows) return;
    const float* xn = xn_ + (size_t)row * NFEAT;
    const float* xc = xc_ + (size_t)row * NCAT;
    unsigned short* ph = oh + (size_t)row * KP_IN;
    unsigned short* pl = ol + (size_t)row * KP_IN;
    if (lane < NFEAT) {
        float x = xn[lane];
        float cs[NFREQ], sn[NFREQ];
        #pragma unroll
        for (int j = 0; j < NFREQ; j++) {
            float p = 6.28318530717958647692f * sF[lane * NFREQ + j] * x;
            sn[j] = __sinf(p);
            cs[j] = __cosf(p);
        }
        #pragma unroll
        for (int d = 0; d < DEMB; d++) {
            float acc = sB[d];
            #pragma unroll
            for (int j = 0; j < NFREQ; j++)
                acc = fmaf(cs[j], sW[j * DEMB + d], fmaf(sn[j], sW[(NFREQ + j) * DEMB + d], acc));
            float v = fmaxf(acc, 0.f);
            unsigned short h = f2bf(v);
            ph[lane * DEMB + d] = h;
            pl[lane * DEMB + d] = f2bf(v - bf2f(h));
        }
    }
    if (lane < NCAT) {
        float v = xc[lane];
        unsigned short h = f2bf(v);
        ph[800 + lane] = h;
        pl[800 + lane] = f2bf(v - bf2f(h));
    }
    if (lane >= NCAT && lane < 32) {
        ph[800 + lane] = 0;
        pl[800 + lane] = 0;
    }
}

// ---------------------------------------------------------------- bf16 MFMA GEMM (plain, 128 tile)
__global__ __launch_bounds__(256) void bgemm_kernel(
    const unsigned short* __restrict__ A, const unsigned short* __restrict__ Bt,
    int M, int N, int Kp,
    float* __restrict__ Cf, unsigned short* __restrict__ Cb,
    const float* __restrict__ bias, int flags)
{
    __shared__ unsigned short As[128 * 32];
    __shared__ unsigned short Bs[128 * 32];
    int tid = threadIdx.x;
    int w = tid >> 6, lane = tid & 63;
    int m0 = blockIdx.y * 128, n0 = blockIdx.x * 128;
    int wr = (w >> 1) * 64, wc = (w & 1) * 64;

    f32x4 acc[4][4];
    #pragma unroll
    for (int i = 0; i < 4; i++)
        #pragma unroll
        for (int j = 0; j < 4; j++) acc[i][j] = (f32x4){0.f, 0.f, 0.f, 0.f};

    int srow = w * 32 + (lane >> 2);
    int scol = (lane & 3) * 8;
    const unsigned short* pa0 = A  + (size_t)min(m0 + srow,      M - 1) * Kp + scol;
    const unsigned short* pa1 = A  + (size_t)min(m0 + srow + 16, M - 1) * Kp + scol;
    const unsigned short* pb0 = Bt + (size_t)min(n0 + srow,      N - 1) * Kp + scol;
    const unsigned short* pb1 = Bt + (size_t)min(n0 + srow + 16, N - 1) * Kp + scol;
    unsigned short* la0 = &As[(w * 32) * 32];
    unsigned short* la1 = &As[(w * 32 + 16) * 32];
    unsigned short* lb0 = &Bs[(w * 32) * 32];
    unsigned short* lb1 = &Bs[(w * 32 + 16) * 32];

    int fr = lane & 15, q = lane >> 4;

    for (int k0 = 0; k0 < Kp; k0 += 32) {
        __syncthreads();
        GLDS16(pa0 + k0, la0);
        GLDS16(pa1 + k0, la1);
        GLDS16(pb0 + k0, lb0);
        GLDS16(pb1 + k0, lb1);
        __syncthreads();
        short8 a[4], b[4];
        #pragma unroll
        for (int i = 0; i < 4; i++)
            a[i] = *(const short8*)&As[(wr + i * 16 + fr) * 32 + q * 8];
        #pragma unroll
        for (int j = 0; j < 4; j++)
            b[j] = *(const short8*)&Bs[(wc + j * 16 + fr) * 32 + q * 8];
        #pragma unroll
        for (int i = 0; i < 4; i++)
            #pragma unroll
            for (int j = 0; j < 4; j++)
                acc[i][j] = __builtin_amdgcn_mfma_f32_16x16x32_bf16(a[i], b[j], acc[i][j], 0, 0, 0);
    }

    int col = lane & 15, rq = (lane >> 4) * 4;
    #pragma unroll
    for (int i = 0; i < 4; i++)
        #pragma unroll
        for (int j = 0; j < 4; j++) {
            int n_g = n0 + wc + j * 16 + col;
            #pragma unroll
            for (int r = 0; r < 4; r++) {
                int m_g = m0 + wr + i * 16 + rq + r;
                if (m_g < M && n_g < N) {
                    float v = acc[i][j][r];
                    if (bias) v += bias[n_g];
                    if (flags & BG_RELU) v = fmaxf(v, 0.f);
                    if (Cf) Cf[(size_t)m_g * N + n_g] = v;
                    if (Cb) Cb[(size_t)m_g * N + n_g] = f2bf(v);
                }
            }
        }
}

// ------------------------------------------- bf16 MFMA GEMM, 3-term split, 128 tile
__global__ __launch_bounds__(256) void bgemm3_kernel(
    const unsigned short* __restrict__ Ah, const unsigned short* __restrict__ Al,
    const unsigned short* __restrict__ Bh, const unsigned short* __restrict__ Bl,
    int M, int N, int Kp,
    float* __restrict__ Cf, unsigned short* __restrict__ Cbh, unsigned short* __restrict__ Cbl,
    const float* __restrict__ bias, const float* __restrict__ resf,
    const float* __restrict__ cnorm, int flags)
{
    __shared__ unsigned short Ash[128 * 32];
    __shared__ unsigned short Asl[128 * 32];
    __shared__ unsigned short Bsh[128 * 32];
    __shared__ unsigned short Bsl[128 * 32];
    int tid = threadIdx.x;
    int w = tid >> 6, lane = tid & 63;
    int m0 = blockIdx.y * 128, n0 = blockIdx.x * 128;
    int wr = (w >> 1) * 64, wc = (w & 1) * 64;

    f32x4 acc[4][4];
    #pragma unroll
    for (int i = 0; i < 4; i++)
        #pragma unroll
        for (int j = 0; j < 4; j++) acc[i][j] = (f32x4){0.f, 0.f, 0.f, 0.f};

    int srow = w * 32 + (lane >> 2);
    int scol = (lane & 3) * 8;
    size_t ra0 = (size_t)min(m0 + srow,      M - 1) * Kp + scol;
    size_t ra1 = (size_t)min(m0 + srow + 16, M - 1) * Kp + scol;
    size_t rb0 = (size_t)min(n0 + srow,      N - 1) * Kp + scol;
    size_t rb1 = (size_t)min(n0 + srow + 16, N - 1) * Kp + scol;
    unsigned short* lah0 = &Ash[(w * 32) * 32];
    unsigned short* lah1 = &Ash[(w * 32 + 16) * 32];
    unsigned short* lal0 = &Asl[(w * 32) * 32];
    unsigned short* lal1 = &Asl[(w * 32 + 16) * 32];
    unsigned short* lbh0 = &Bsh[(w * 32) * 32];
    unsigned short* lbh1 = &Bsh[(w * 32 + 16) * 32];
    unsigned short* lbl0 = &Bsl[(w * 32) * 32];
    unsigned short* lbl1 = &Bsl[(w * 32 + 16) * 32];

    int fr = lane & 15, q = lane >> 4;

    for (int k0 = 0; k0 < Kp; k0 += 32) {
        __syncthreads();
        GLDS16(Ah + ra0 + k0, lah0);
        GLDS16(Ah + ra1 + k0, lah1);
        GLDS16(Al + ra0 + k0, lal0);
        GLDS16(Al + ra1 + k0, lal1);
        GLDS16(Bh + rb0 + k0, lbh0);
        GLDS16(Bh + rb1 + k0, lbh1);
        GLDS16(Bl + rb0 + k0, lbl0);
        GLDS16(Bl + rb1 + k0, lbl1);
        __syncthreads();
        short8 a[4], b[4];
        #pragma unroll
        for (int i = 0; i < 4; i++)
            a[i] = *(const short8*)&Ash[(wr + i * 16 + fr) * 32 + q * 8];
        #pragma unroll
        for (int j = 0; j < 4; j++)
            b[j] = *(const short8*)&Bsh[(wc + j * 16 + fr) * 32 + q * 8];
        #pragma unroll
        for (int i = 0; i < 4; i++)
            #pragma unroll
            for (int j = 0; j < 4; j++)
                acc[i][j] = __builtin_amdgcn_mfma_f32_16x16x32_bf16(a[i], b[j], acc[i][j], 0, 0, 0);
        short8 al[4];
        #pragma unroll
        for (int i = 0; i < 4; i++)
            al[i] = *(const short8*)&Asl[(wr + i * 16 + fr) * 32 + q * 8];
        #pragma unroll
        for (int i = 0; i < 4; i++)
            #pragma unroll
            for (int j = 0; j < 4; j++)
                acc[i][j] = __builtin_amdgcn_mfma_f32_16x16x32_bf16(al[i], b[j], acc[i][j], 0, 0, 0);
        short8 bl[4];
        #pragma unroll
        for (int j = 0; j < 4; j++)
            bl[j] = *(const short8*)&Bsl[(wc + j * 16 + fr) * 32 + q * 8];
        #pragma unroll
        for (int i = 0; i < 4; i++)
            #pragma unroll
            for (int j = 0; j < 4; j++)
                acc[i][j] = __builtin_amdgcn_mfma_f32_16x16x32_bf16(a[i], bl[j], acc[i][j], 0, 0, 0);
    }

    int col = lane & 15, rq = (lane >> 4) * 4;
    #pragma unroll
    for (int i = 0; i < 4; i++)
        #pragma unroll
        for (int j = 0; j < 4; j++) {
            int n_g = n0 + wc + j * 16 + col;
            #pragma unroll
            for (int r = 0; r < 4; r++) {
                int m_g = m0 + wr + i * 16 + rq + r;
                if (m_g < M && n_g < N) {
                    float v = acc[i][j][r];
                    if (bias) v += bias[n_g];
                    if (resf) v += resf[(size_t)m_g * N + n_g];
                    if (flags & BG_RELU) v = fmaxf(v, 0.f);
                    if (flags & BG_SCORE) v = 2.f * v - cnorm[n_g];
                    if (Cf) Cf[(size_t)m_g * N + n_g] = v;
                    if (Cbh) {
                        unsigned short h = f2bf(v);
                        Cbh[(size_t)m_g * N + n_g] = h;
                        if (Cbl) Cbl[(size_t)m_g * N + n_g] = f2bf(v - bf2f(h));
                    }
                }
            }
        }
}

// ------------------------- small-M GEMM: 64x64 tile, 1- or 3-term (Al null => 1-term)
__global__ __launch_bounds__(256) void bgemm3s_kernel(
    const unsigned short* __restrict__ Ah, const unsigned short* __restrict__ Al,
    const unsigned short* __restrict__ Bh, const unsigned short* __restrict__ Bl,
    int M, int N, int Kp,
    float* __restrict__ Cf, unsigned short* __restrict__ Cbh, unsigned short* __restrict__ Cbl,
    const float* __restrict__ bias, const float* __restrict__ resf, int flags)
{
    __shared__ unsigned short Ash[64 * 32];
    __shared__ unsigned short Asl[64 * 32];
    __shared__ unsigned short Bsh[64 * 32];
    __shared__ unsigned short Bsl[64 * 32];
    int tid = threadIdx.x;
    int w = tid >> 6, lane = tid & 63;
    int m0 = blockIdx.y * 64, n0 = blockIdx.x * 64;
    int wr = (w >> 1) * 32, wc = (w & 1) * 32;
    int three = (Al != nullptr);

    f32x4 acc[2][2];
    #pragma unroll
    for (int i = 0; i < 2; i++)
        #pragma unroll
        for (int j = 0; j < 2; j++) acc[i][j] = (f32x4){0.f, 0.f, 0.f, 0.f};

    int srow = w * 16 + (lane >> 2);
    int scol = (lane & 3) * 8;
    size_t ra = (size_t)min(m0 + srow, M - 1) * Kp + scol;
    size_t rb = (size_t)min(n0 + srow, N - 1) * Kp + scol;
    unsigned short* lah = &Ash[(w * 16) * 32];
    unsigned short* lal = &Asl[(w * 16) * 32];
    unsigned short* lbh = &Bsh[(w * 16) * 32];
    unsigned short* lbl = &Bsl[(w * 16) * 32];

    int fr = lane & 15, q = lane >> 4;

    for (int k0 = 0; k0 < Kp; k0 += 32) {
        __syncthreads();
        GLDS16(Ah + ra + k0, lah);
        GLDS16(Bh + rb + k0, lbh);
        if (three) {
            GLDS16(Al + ra + k0, lal);
            GLDS16(Bl + rb + k0, lbl);
        }
        __syncthreads();
        short8 a[2], b[2];
        #pragma unroll
        for (int i = 0; i < 2; i++)
            a[i] = *(const short8*)&Ash[(wr + i * 16 + fr) * 32 + q * 8];
        #pragma unroll
        for (int j = 0; j < 2; j++)
            b[j] = *(const short8*)&Bsh[(wc + j * 16 + fr) * 32 + q * 8];
        #pragma unroll
        for (int i = 0; i < 2; i++)
            #pragma unroll
            for (int j = 0; j < 2; j++)
                acc[i][j] = __builtin_amdgcn_mfma_f32_16x16x32_bf16(a[i], b[j], acc[i][j], 0, 0, 0);
        if (three) {
            short8 al2[2], bl2[2];
            #pragma unroll
            for (int i = 0; i < 2; i++)
                al2[i] = *(const short8*)&Asl[(wr + i * 16 + fr) * 32 + q * 8];
            #pragma unroll
            for (int j = 0; j < 2; j++)
                bl2[j] = *(const short8*)&Bsl[(wc + j * 16 + fr) * 32 + q * 8];
            #pragma unroll
            for (int i = 0; i < 2; i++)
                #pragma unroll
                for (int j = 0; j < 2; j++) {
                    acc[i][j] = __builtin_amdgcn_mfma_f32_16x16x32_bf16(al2[i], b[j], acc[i][j], 0, 0, 0);
                    acc[i][j] = __builtin_amdgcn_mfma_f32_16x16x32_bf16(a[i], bl2[j], acc[i][j], 0, 0, 0);
                }
        }
    }

    int col = lane & 15, rq = (lane >> 4) * 4;
    #pragma unroll
    for (int i = 0; i < 2; i++)
        #pragma unroll
        for (int j = 0; j < 2; j++) {
            int n_g = n0 + wc + j * 16 + col;
            #pragma unroll
            for (int r = 0; r < 4; r++) {
                int m_g = m0 + wr + i * 16 + rq + r;
                if (m_g < M && n_g < N) {
                    float v = acc[i][j][r];
                    if (bias) v += bias[n_g];
                    if (resf) v += resf[(size_t)m_g * N + n_g];
                    if (flags & BG_RELU) v = fmaxf(v, 0.f);
                    if (Cf) Cf[(size_t)m_g * N + n_g] = v;
                    if (Cbh) {
                        unsigned short h = f2bf(v);
                        Cbh[(size_t)m_g * N + n_g] = h;
                        if (Cbl) Cbl[(size_t)m_g * N + n_g] = f2bf(v - bf2f(h));
                    }
                }
            }
        }
}

// ---------------------------------------------------------------- LayerNorm bf16 hi/lo out
__global__ __launch_bounds__(256) void ln_split_kernel(const float* __restrict__ X,
    unsigned short* __restrict__ Yh, unsigned short* __restrict__ Yl,
    const float* __restrict__ g, const float* __restrict__ bt, int M)
{
    int wave = threadIdx.x >> 6, lane = threadIdx.x & 63;
    int row = blockIdx.x * 4 + wave;
    if (row >= M) return;
    const float* x = X + (size_t)row * DM;
    float4 v0 = ((const float4*)x)[lane * 2];
    float4 v1 = ((const float4*)x)[lane * 2 + 1];
    float s = v0.x + v0.y + v0.z + v0.w + v1.x + v1.y + v1.z + v1.w;
    #pragma unroll
    for (int off = 32; off; off >>= 1) s += __shfl_xor(s, off, 64);
    float m = s * (1.f / DM);
    float q = (v0.x - m) * (v0.x - m) + (v0.y - m) * (v0.y - m)
            + (v0.z - m) * (v0.z - m) + (v0.w - m) * (v0.w - m)
            + (v1.x - m) * (v1.x - m) + (v1.y - m) * (v1.y - m)
            + (v1.z - m) * (v1.z - m) + (v1.w - m) * (v1.w - m);
    #pragma unroll
    for (int off = 32; off; off >>= 1) q += __shfl_xor(q, off, 64);
    float rstd = 1.f / sqrtf(q * (1.f / DM) + 1e-5f);
    float vals[8] = {v0.x, v0.y, v0.z, v0.w, v1.x, v1.y, v1.z, v1.w};
    unsigned short* yh = Yh + (size_t)row * DM + lane * 8;
    unsigned short* yl = Yl + (size_t)row * DM + lane * 8;
    const float* gp = g + lane * 8;
    const float* bp = bt + lane * 8;
    #pragma unroll
    for (int i = 0; i < 8; i++) {
        float y = (vals[i] - m) * rstd * gp[i] + bp[i];
        unsigned short h = f2bf(y);
        yh[i] = h;
        yl[i] = f2bf(y - bf2f(h));
    }
}

// ---------------------------------------------------------------- key norms (fp32 k)
__global__ __launch_bounds__(256) void cnorm_kernel(const float* __restrict__ Kc,
    float* __restrict__ cn, int N)
{
    int wave = threadIdx.x >> 6, lane = threadIdx.x & 63;
    int row = blockIdx.x * 4 + wave;
    if (row >= N) return;
    const float* x = Kc + (size_t)row * DM;
    float4 v0 = ((const float4*)x)[lane * 2];
    float4 v1 = ((const float4*)x)[lane * 2 + 1];
    float s = v0.x * v0.x + v0.y * v0.y + v0.z * v0.z + v0.w * v0.w
            + v1.x * v1.x + v1.y * v1.y + v1.z * v1.z + v1.w * v1.w;
    #pragma unroll
    for (int off = 32; off; off >>= 1) s += __shfl_xor(s, off, 64);
    if (lane == 0) cn[row] = s;
}

// ---------------------------------------------------------------- ctx init
__global__ void ctx_init_kernel(int* __restrict__ idx, float* __restrict__ sc)
{
    int i = blockIdx.x * 256 + threadIdx.x;
    if (i < NB * CTX) { idx[i] = 0; sc[i] = -1e30f; }
}

// ------------------------------------- running top-96 merge
#define NBINS 4096
#define CANDCAP 2048
__global__ __launch_bounds__(256) void topk_merge_kernel(
    const float* __restrict__ S, int m, int base,
    const int* __restrict__ pidx, const float* __restrict__ pscore,
    int* __restrict__ nidx, float* __restrict__ nscore)
{
    __shared__ int   hist[NBINS];
    __shared__ float red[256];
    __shared__ float prev_s[CTX];
    __shared__ int   prev_i[CTX];
    __shared__ float s_mn, s_scale;
    __shared__ int   s_bstar, s_m, nsel, ncnd;
    __shared__ float cnd_s[CANDCAP];
    __shared__ int   cnd_g[CANDCAP];
    __shared__ float sel_s[CTX];
    __shared__ int   sel_g[CTX];

    int b = blockIdx.x, tid = threadIdx.x;
    const float* Sb = S + (size_t)b * m;
    if (tid < CTX) { prev_s[tid] = pscore[b * CTX + tid]; prev_i[tid] = pidx[b * CTX + tid]; }
    for (int i = tid; i < NBINS; i += 256) hist[i] = 0;
    __syncthreads();
    int tot = m + CTX;
    float mn = 1e30f, mx = -1e30f;
    for (int i = tid; i < tot; i += 256) {
        float v = (i < m) ? Sb[i] : prev_s[i - m];
        if (v > -1e29f) { mn = fminf(mn, v); mx = fmaxf(mx, v); }
    }
    red[tid] = mx; __syncthreads();
    for (int s = 128; s > 0; s >>= 1) { if (tid < s) red[tid] = fmaxf(red[tid], red[tid + s]); __syncthreads(); }
    float gmx = red[0]; __syncthreads();
    red[tid] = mn; __syncthreads();
    for (int s = 128; s > 0; s >>= 1) { if (tid < s) red[tid] = fminf(red[tid], red[tid + s]); __syncthreads(); }
    float gmn = red[0]; __syncthreads();
    if (tid == 0) {
        float w = gmx - gmn;
        if (!(w > 0.f)) w = 1.f;
        s_mn = gmn;
        s_scale = (float)NBINS / w * 0.9999990f;
        nsel = 0; ncnd = 0;
    }
    __syncthreads();
    float lmn = s_mn, lsc = s_scale;
    for (int i = tid; i < tot; i += 256) {
        float v = (i < m) ? Sb[i] : prev_s[i - m];
        if (v <= -1e29f) continue;
        int bin = (int)((v - lmn) * lsc);
        bin = max(0, min(NBINS - 1, bin));
        atomicAdd(&hist[bin], 1);
    }
    __syncthreads();
    if (tid == 0) {
        int cum = 0, bb = 0;
        for (int i = NBINS - 1; i >= 0; i--) {
            int h = hist[i];
            if (cum + h >= CTX) { bb = i; break; }
            cum += h;
        }
        s_bstar = bb; s_m = CTX - cum;
    }
    __syncthreads();
    int bstar = s_bstar;
    for (int i = tid; i < tot; i += 256) {
        float v = (i < m) ? Sb[i] : prev_s[i - m];
        if (v <= -1e29f) continue;
        int g = (i < m) ? (base + i) : prev_i[i - m];
        int bin = (int)((v - lmn) * lsc);
        bin = max(0, min(NBINS - 1, bin));
        if (bin > bstar) {
            int p = atomicAdd(&nsel, 1);
            sel_s[p] = v; sel_g[p] = g;
        } else if (bin == bstar) {
            int p = atomicAdd(&ncnd, 1);
            if (p < CANDCAP) { cnd_s[p] = v; cnd_g[p] = g; }
        }
    }
    __syncthreads();
    int msel = s_m;
    int nc = min(ncnd, CANDCAP);
    for (int i = tid; i < nc; i += 256) {
        float si = cnd_s[i]; int gi = cnd_g[i];
        int rank = 0;
        for (int j = 0; j < nc; j++) {
            float sj = cnd_s[j];
            rank += (sj > si) || (sj == si && cnd_g[j] < gi);
        }
        if (rank < msel) {
            int p = atomicAdd(&nsel, 1);
            sel_s[p] = si; sel_g[p] = gi;
        }
    }
    __syncthreads();
    if (tid < CTX) {
        nidx[b * CTX + tid] = sel_g[tid];
        nscore[b * CTX + tid] = sel_s[tid];
    }
}

// ------------------------------- softmax + label/value context aggregation
// s_out now written as bf16 hi/lo (input to the T_w2 split GEMM)
__global__ __launch_bounds__(256) void agg_kernel(
    const int* __restrict__ ctx_idx, const float* __restrict__ ctx_score,
    const float* __restrict__ cand_y, const float* __restrict__ T1b,
    const unsigned short* __restrict__ T1c, const float* __restrict__ T_b1,
    const float* __restrict__ x_batch,
    const float* __restrict__ label_w, const float* __restrict__ label_b,
    unsigned short* __restrict__ s_h, unsigned short* __restrict__ s_l,
    float* __restrict__ u_out)
{
    __shared__ float p_s[CTX];
    __shared__ int   p_i[CTX];
    __shared__ float s_ybar;
    int b = blockIdx.x, tid = threadIdx.x;
    if (tid < CTX) { p_s[tid] = ctx_score[b * CTX + tid]; p_i[tid] = ctx_idx[b * CTX + tid]; }
    __syncthreads();
    if (tid == 0) {
        float mx = -1e30f;
        for (int c = 0; c < CTX; c++) mx = fmaxf(mx, p_s[c]);
        float sum = 0.f;
        for (int c = 0; c < CTX; c++) { float e = __expf(p_s[c] - mx); p_s[c] = e; sum += e; }
        float inv = 1.f / sum, yb = 0.f;
        for (int c = 0; c < CTX; c++) { p_s[c] *= inv; yb += p_s[c] * cand_y[p_i[c]]; }
        s_ybar = yb;
    }
    __syncthreads();
    int j = tid * 4;
    float4 kv = *(const float4*)(T1b + (size_t)b * DBK + j);
    float4 tb = *(const float4*)(T_b1 + j);
    float base0 = kv.x + tb.x, base1 = kv.y + tb.y, base2 = kv.z + tb.z, base3 = kv.w + tb.w;
    float a0 = 0.f, a1 = 0.f, a2 = 0.f, a3 = 0.f;
    for (int c = 0; c < CTX; c++) {
        float p = p_s[c];
        ushort4 cu = *(const ushort4*)(T1c + (size_t)p_i[c] * DBK + j);
        a0 = fmaf(p, fmaxf(base0 - bf2f(cu.x), 0.f), a0);
        a1 = fmaf(p, fmaxf(base1 - bf2f(cu.y), 0.f), a1);
        a2 = fmaf(p, fmaxf(base2 - bf2f(cu.z), 0.f), a2);
        a3 = fmaf(p, fmaxf(base3 - bf2f(cu.w), 0.f), a3);
    }
    {
        ushort4 oh, ol;
        oh.x = f2bf(a0); ol.x = f2bf(a0 - bf2f(oh.x));
        oh.y = f2bf(a1); ol.y = f2bf(a1 - bf2f(oh.y));
        oh.z = f2bf(a2); ol.z = f2bf(a2 - bf2f(oh.z));
        oh.w = f2bf(a3); ol.w = f2bf(a3 - bf2f(oh.w));
        *(ushort4*)(s_h + (size_t)b * DBK + j) = oh;
        *(ushort4*)(s_l + (size_t)b * DBK + j) = ol;
    }
    if (tid < 128) {
        int d = tid * 4;
        float4 xv = *(const float4*)(x_batch + (size_t)b * DM + d);
        float4 lw = *(const float4*)(label_w + d);
        float4 lb = *(const float4*)(label_b + d);
        float yb = s_ybar;
        *(float4*)(u_out + (size_t)b * DM + d) =
            make_float4(xv.x + yb * lw.x + lb.x, xv.y + yb * lw.y + lb.y,
                        xv.z + yb * lw.z + lb.z, xv.w + yb * lw.w + lb.w);
    }
}

// ---------------------------------------------------------------- head
__global__ __launch_bounds__(256) void head_kernel(
    const float* __restrict__ X, const float* __restrict__ g,
    const float* __restrict__ bt, const float* __restrict__ w,
    const float* __restrict__ hb, float* __restrict__ out, int M)
{
    int wave = threadIdx.x >> 6, lane = threadIdx.x & 63;
    int row = blockIdx.x * 4 + wave;
    if (row >= M) return;
    const float* x = X + (size_t)row * DM;
    float4 v0 = ((const float4*)x)[lane * 2];
    float4 v1 = ((const float4*)x)[lane * 2 + 1];
    float s = v0.x + v0.y + v0.z + v0.w + v1.x + v1.y + v1.z + v1.w;
    #pragma unroll
    for (int off = 32; off; off >>= 1) s += __shfl_xor(s, off, 64);
    float m = s * (1.f / DM);
    float q = (v0.x - m) * (v0.x - m) + (v0.y - m) * (v0.y - m)
            + (v0.z - m) * (v0.z - m) + (v0.w - m) * (v0.w - m)
            + (v1.x - m) * (v1.x - m) + (v1.y - m) * (v1.y - m)
            + (v1.z - m) * (v1.z - m) + (v1.w - m) * (v1.w - m);
    #pragma unroll
    for (int off = 32; off; off >>= 1) q += __shfl_xor(q, off, 64);
    float rstd = 1.f / sqrtf(q * (1.f / DM) + 1e-5f);
    float4 g0 = ((const float4*)g)[lane * 2], g1 = ((const float4*)g)[lane * 2 + 1];
    float4 b0 = ((const float4*)bt)[lane * 2], b1 = ((const float4*)bt)[lane * 2 + 1];
    float4 w0 = ((const float4*)w)[lane * 2], w1 = ((const float4*)w)[lane * 2 + 1];
    float t = 0.f;
    t += fmaxf((v0.x - m) * rstd * g0.x + b0.x, 0.f) * w0.x;
    t += fmaxf((v0.y - m) * rstd * g0.y + b0.y, 0.f) * w0.y;
    t += fmaxf((v0.z - m) * rstd * g0.z + b0.z, 0.f) * w0.z;
    t += fmaxf((v0.w - m) * rstd * g0.w + b0.w, 0.f) * w0.w;
    t += fmaxf((v1.x - m) * rstd * g1.x + b1.x, 0.f) * w1.x;
    t += fmaxf((v1.y - m) * rstd * g1.y + b1.y, 0.f) * w1.y;
    t += fmaxf((v1.z - m) * rstd * g1.z + b1.z, 0.f) * w1.z;
    t += fmaxf((v1.w - m) * rstd * g1.w + b1.w, 0.f) * w1.w;
    #pragma unroll
    for (int off = 32; off; off >>= 1) t += __shfl_xor(t, off, 64);
    if (lane == 0) out[row] = t + hb[0];
}

// =================================================================== host
extern "C" void kernel_launch(void* const* d_in, const int* in_sizes, int n_in,
                              void* d_out, int out_size, void* d_ws, size_t ws_size,
                              hipStream_t stream) {
    (void)in_sizes; (void)n_in; (void)out_size;
    const float* x_num   = (const float*)d_in[0];
    const float* x_cat   = (const float*)d_in[1];
    const float* cxn     = (const float*)d_in[2];
    const float* cxc     = (const float*)d_in[3];
    const float* cand_y  = (const float*)d_in[4];
    const float* freq    = (const float*)d_in[6];
    const float* plr_w   = (const float*)d_in[7];
    const float* plr_b   = (const float*)d_in[8];
    const float* lin_w   = (const float*)d_in[9];
    const float* lin_b   = (const float*)d_in[10];
    const float* enc_w1  = (const float*)d_in[11];
    const float* enc_b1  = (const float*)d_in[12];
    const float* enc_w2  = (const float*)d_in[13];
    const float* enc_b2  = (const float*)d_in[14];
    const float* mix_g   = (const float*)d_in[15];
    const float* mix_b   = (const float*)d_in[16];
    const float* K_w     = (const float*)d_in[17];
    const float* K_b     = (const float*)d_in[18];
    const float* label_w = (const float*)d_in[19];
    const float* label_b = (const float*)d_in[20];
    const float* T_w1    = (const float*)d_in[21];
    const float* T_b1    = (const float*)d_in[22];
    const float* T_w2    = (const float*)d_in[23];
    const float* pred_g  = (const float*)d_in[24];
    const float* pred_b  = (const float*)d_in[25];
    const float* pred_w1 = (const float*)d_in[26];
    const float* pred_b1 = (const float*)d_in[27];
    const float* pred_w2 = (const float*)d_in[28];
    const float* pred_b2 = (const float*)d_in[29];
    const float* head_g  = (const float*)d_in[30];
    const float* head_b  = (const float*)d_in[31];
    const float* head_w  = (const float*)d_in[32];
    const float* head_bias = (const float*)d_in[33];
    float* out = (float*)d_out;

    char* ws = (char*)d_ws;
    size_t off = 0;
    auto alloc = [&](size_t n) { char* p = ws + off; off = (off + n + 255) & ~(size_t)255; return p; };

    typedef unsigned short u16;
    // --- bf16 weights (transposed to N x Kp), hi/lo ---
    u16* lin_wt_h = (u16*)alloc((size_t)DM * KP_IN * 2);
    u16* lin_wt_l = (u16*)alloc((size_t)DM * KP_IN * 2);
    u16* e1t_h    = (u16*)alloc((size_t)DBK * DM * 2);
    u16* e1t_l    = (u16*)alloc((size_t)DBK * DM * 2);
    u16* e2t_h    = (u16*)alloc((size_t)DM * DBK * 2);
    u16* e2t_l    = (u16*)alloc((size_t)DM * DBK * 2);
    u16* K_wt_h   = (u16*)alloc((size_t)DM * DM * 2);
    u16* K_wt_l   = (u16*)alloc((size_t)DM * DM * 2);
    u16* T_w1t    = (u16*)alloc((size_t)DBK * DM * 2);
    u16* T_w2t_h  = (u16*)alloc((size_t)DM * DBK * 2);
    u16* T_w2t_l  = (u16*)alloc((size_t)DM * DBK * 2);
    u16* p1t_h    = (u16*)alloc((size_t)DBK * DM * 2);
    u16* p1t_l    = (u16*)alloc((size_t)DBK * DM * 2);
    u16* p2t_h    = (u16*)alloc((size_t)DM * DBK * 2);
    u16* p2t_l    = (u16*)alloc((size_t)DM * DBK * 2);
    // --- persistent ---
    u16*   T1c  = (u16*)alloc((size_t)NCAND * DBK * 2);   // 102.4 MB
    float* T1b  = (float*)alloc((size_t)NB * DBK * 4);
    float* xB   = (float*)alloc((size_t)NB * DM * 4);
    u16*   kBh  = (u16*)alloc((size_t)NB * DM * 2);
    u16*   kBl  = (u16*)alloc((size_t)NB * DM * 2);
    // batch scratch
    u16* binh = (u16*)alloc((size_t)NB * KP_IN * 2);
    u16* binl = (u16*)alloc((size_t)NB * KP_IN * 2);
    u16* xBhh = (u16*)alloc((size_t)NB * DM * 2);
    u16* xBhl = (u16*)alloc((size_t)NB * DM * 2);
    u16* hBh  = (u16*)alloc((size_t)NB * DBK * 2);
    u16* hBl  = (u16*)alloc((size_t)NB * DBK * 2);
    u16* lnBh = (u16*)alloc((size_t)NB * DM * 2);
    u16* lnBl = (u16*)alloc((size_t)NB * DM * 2);
    // ctx + tail
    int*   ctxAi = (int*)alloc((size_t)NB * CTX * 4);
    float* ctxAs = (float*)alloc((size_t)NB * CTX * 4);
    int*   ctxBi = (int*)alloc((size_t)NB * CTX * 4);
    float* ctxBs = (float*)alloc((size_t)NB * CTX * 4);
    u16*   sbufh = (u16*)alloc((size_t)NB * DBK * 2);
    u16*   sbufl = (u16*)alloc((size_t)NB * DBK * 2);
    float* ubuf  = (float*)alloc((size_t)NB * DM * 4);
    float* x2    = (float*)alloc((size_t)NB * DM * 4);
    u16*   h2h   = (u16*)alloc((size_t)NB * DM * 2);
    u16*   h2l   = (u16*)alloc((size_t)NB * DM * 2);
    u16*   hph   = (u16*)alloc((size_t)NB * DBK * 2);
    u16*   hpl   = (u16*)alloc((size_t)NB * DBK * 2);
    float* x3    = (float*)alloc((size_t)NB * DM * 4);

    // --- chunk arena (runtime-adaptive, cap 25600 rows) ---
    size_t remain = (ws_size > off + 8192) ? (ws_size - off - 8192) : 0;
    const size_t perrow = (size_t)KP_IN * 4 + (size_t)DM * 4 + (size_t)DM * 4
                        + (size_t)DBK * 4 + (size_t)DM * 4 + (size_t)DM * 4
                        + (size_t)DM * 4 + 8;
    long ncl = (long)(remain / perrow);
    int NC = (int)(ncl > 25600 ? 25600 : ncl);
    NC &= ~127;
    if (NC < 256) NC = 256;
    u16* inCh = (u16*)alloc((size_t)NC * KP_IN * 2);
    u16* inCl = (u16*)alloc((size_t)NC * KP_IN * 2);
    float* xC = (float*)alloc((size_t)NC * DM * 4);
    u16* xCh  = (u16*)alloc((size_t)NC * DM * 2);
    u16* xCl  = (u16*)alloc((size_t)NC * DM * 2);
    u16* hCh  = (u16*)alloc((size_t)NC * DBK * 2);
    u16* hCl  = (u16*)alloc((size_t)NC * DBK * 2);
    u16* lnCh = (u16*)alloc((size_t)NC * DM * 2);
    u16* lnCl = (u16*)alloc((size_t)NC * DM * 2);
    float* kC = (float*)alloc((size_t)NC * DM * 4);
    u16* kCh  = (u16*)alloc((size_t)NC * DM * 2);
    u16* kCl  = (u16*)alloc((size_t)NC * DM * 2);
    float* cnC = (float*)alloc((size_t)NC * 4);
    // scoresC (NB x NC fp32 = 2048*NC B) aliases inCh+inCl (3328*NC B contiguous)
    float* scoresC = (float*)inCh;

    auto bgemm = [&](const u16* A, const u16* Bt, int M, int N, int Kp,
                     float* Cf, u16* Cb, const float* bias, int flags) {
        dim3 grid((N + 127) / 128, (M + 127) / 128);
        bgemm_kernel<<<grid, 256, 0, stream>>>(A, Bt, M, N, Kp, Cf, Cb, bias, flags);
    };
    auto bgemm3 = [&](const u16* Ah, const u16* Al, const u16* Bh, const u16* Bl,
                      int M, int N, int Kp, float* Cf, u16* Cbh, u16* Cbl,
                      const float* bias, const float* resf, const float* cnorm, int flags) {
        dim3 grid((N + 127) / 128, (M + 127) / 128);
        bgemm3_kernel<<<grid, 256, 0, stream>>>(Ah, Al, Bh, Bl, M, N, Kp,
                                                Cf, Cbh, Cbl, bias, resf, cnorm, flags);
    };
    auto bgemm3s = [&](const u16* Ah, const u16* Al, const u16* Bh, const u16* Bl,
                       int M, int N, int Kp, float* Cf, u16* Cbh, u16* Cbl,
                       const float* bias, const float* resf, int flags) {
        dim3 grid((N + 63) / 64, (M + 63) / 64);
        bgemm3s_kernel<<<grid, 256, 0, stream>>>(Ah, Al, Bh, Bl, M, N, Kp,
                                                 Cf, Cbh, Cbl, bias, resf, flags);
    };
    auto wprep = [&](const float* W, int K, int N, int Kp, u16* Wh, u16* Wl) {
        int n = N * Kp;
        wprep_kernel<<<(n + 255) / 256, 256, 0, stream>>>(W, K, N, Kp, Wh, Wl);
    };

    // ---------- weight prep ----------
    wprep(lin_w, DIN, DM, KP_IN, lin_wt_h, lin_wt_l);
    wprep(enc_w1, DM, DBK, DM, e1t_h, e1t_l);
    wprep(enc_w2, DBK, DM, DBK, e2t_h, e2t_l);
    wprep(K_w, DM, DM, DM, K_wt_h, K_wt_l);
    wprep(T_w1, DM, DBK, DM, T_w1t, nullptr);
    wprep(T_w2, DBK, DM, DBK, T_w2t_h, T_w2t_l);
    wprep(pred_w1, DM, DBK, DM, p1t_h, p1t_l);
    wprep(pred_w2, DBK, DM, DBK, p2t_h, p2t_l);

    // ---------- batch encode (64-tile split GEMMs) ----------
    plr_bf16_kernel<<<(NB + 3) / 4, 256, 0, stream>>>(x_num, x_cat, NB, freq, plr_w, plr_b, binh, binl);
    bgemm3s(binh, binl, lin_wt_h, lin_wt_l, NB, DM, KP_IN, xB, xBhh, xBhl, lin_b, nullptr, 0);
    bgemm3s(xBhh, xBhl, e1t_h, e1t_l, NB, DBK, DM, nullptr, hBh, hBl, enc_b1, nullptr, BG_RELU);
    bgemm3s(hBh, hBl, e2t_h, e2t_l, NB, DM, DBK, xB, nullptr, nullptr, enc_b2, xB, 0);
    ln_split_kernel<<<(NB + 3) / 4, 256, 0, stream>>>(xB, lnBh, lnBl, mix_g, mix_b, NB);
    bgemm3s(lnBh, lnBl, K_wt_h, K_wt_l, NB, DM, DM, nullptr, kBh, kBl, K_b, nullptr, 0);
    bgemm3s(kBh, nullptr, T_w1t, nullptr, NB, DBK, DM, T1b, nullptr, nullptr, nullptr, nullptr, 0);
    ctx_init_kernel<<<(NB * CTX + 255) / 256, 256, 0, stream>>>(ctxAi, ctxAs);

    // ---------- candidate chunks (128-tile GEMMs) ----------
    const int* pI = ctxAi; const float* pS = ctxAs;
    int* nI = ctxBi; float* nS = ctxBs;
    int nch = (NCAND + NC - 1) / NC;
    for (int c = 0; c < nch; c++) {
        int s = c * NC;
        int m = NCAND - s; if (m > NC) m = NC;
        plr_bf16_kernel<<<(m + 3) / 4, 256, 0, stream>>>(cxn + (size_t)s * NFEAT,
                                                         cxc + (size_t)s * NCAT,
                                                         m, freq, plr_w, plr_b, inCh, inCl);
        bgemm3(inCh, inCl, lin_wt_h, lin_wt_l, m, DM, KP_IN, xC, xCh, xCl, lin_b, nullptr, nullptr, 0);
        bgemm3(xCh, xCl, e1t_h, e1t_l, m, DBK, DM, nullptr, hCh, hCl, enc_b1, nullptr, nullptr, BG_RELU);
        bgemm3(hCh, hCl, e2t_h, e2t_l, m, DM, DBK, xC, nullptr, nullptr, enc_b2, xC, nullptr, 0);
        ln_split_kernel<<<(m + 3) / 4, 256, 0, stream>>>(xC, lnCh, lnCl, mix_g, mix_b, m);
        bgemm3(lnCh, lnCl, K_wt_h, K_wt_l, m, DM, DM, kC, kCh, kCl, K_b, nullptr, nullptr, 0);
        cnorm_kernel<<<(m + 3) / 4, 256, 0, stream>>>(kC, cnC, m);
        bgemm(kCh, T_w1t, m, DBK, DM, nullptr, T1c + (size_t)s * DBK, nullptr, 0);
        // scoresC overwrites inCh/inCl — both dead after lin GEMM above
        bgemm3(kBh, kBl, kCh, kCl, NB, m, DM, scoresC, nullptr, nullptr,
               nullptr, nullptr, cnC, BG_SCORE);
        topk_merge_kernel<<<NB, 256, 0, stream>>>(scoresC, m, s, pI, pS, nI, nS);
        { const int* t = pI; pI = nI; nI = (int*)t; }
        { const float* t = pS; pS = nS; nS = (float*)t; }
    }

    // ---------- aggregation + predictor + head (64-tile split GEMMs) ----------
    agg_kernel<<<NB, 256, 0, stream>>>(pI, pS, cand_y, T1b, T1c, T_b1,
                                       xB, label_w, label_b, sbufh, sbufl, ubuf);
    bgemm3s(sbufh, sbufl, T_w2t_h, T_w2t_l, NB, DM, DBK, x2, nullptr, nullptr,
            nullptr, ubuf, 0);
    ln_split_kernel<<<(NB + 3) / 4, 256, 0, stream>>>(x2, h2h, h2l, pred_g, pred_b, NB);
    bgemm3s(h2h, h2l, p1t_h, p1t_l, NB, DBK, DM, nullptr, hph, hpl, pred_b1, nullptr, BG_RELU);
    bgemm3s(hph, hpl, p2t_h, p2t_l, NB, DM, DBK, x3, nullptr, nullptr, pred_b2, x2, 0);
    head_kernel<<<(NB + 3) / 4, 256, 0, stream>>>(x3, head_g, head_b, head_w, head_bias, out, NB);
}

// Round 7
// 2194.696 us; speedup vs baseline: 3.2987x; 1.3395x over previous
//
#include <hip/hip_runtime.h>

#define NCAND 50000
#define NB    512
#define DIN   820
#define KP_IN 832
#define DM    512
#define DBK   1024
#define NFEAT 50
#define NCAT  20
#define NFREQ 16
#define DEMB  16
#define CTX   96

typedef __attribute__((ext_vector_type(8))) short short8;
typedef __attribute__((ext_vector_type(4))) float f32x4;

static __device__ __forceinline__ unsigned short f2bf(float f) {
    union { float f; unsigned int i; } u; u.f = f;
    unsigned int r = u.i + 0x7FFFu + ((u.i >> 16) & 1u);
    return (unsigned short)(r >> 16);
}
static __device__ __forceinline__ float bf2f(unsigned short s) {
    union { unsigned int i; float f; } u; u.i = ((unsigned int)s) << 16;
    return u.f;
}
// order-preserving float->uint key (ascending)
static __device__ __forceinline__ unsigned int f2key(float f) {
    union { float f; unsigned int i; } u; u.f = f;
    return (u.i & 0x80000000u) ? ~u.i : (u.i | 0x80000000u);
}
static __device__ __forceinline__ float key2f(unsigned int k) {
    union { unsigned int i; float f; } u;
    u.i = (k & 0x80000000u) ? (k ^ 0x80000000u) : ~k;
    return u.f;
}

#define GLDS16(g, l) __builtin_amdgcn_global_load_lds( \
    (const __attribute__((address_space(1))) void*)(g), \
    (__attribute__((address_space(3))) void*)(l), 16, 0, 0)

#define BG_RELU  1
#define BG_SCORE 2

// LDS chunk swizzle: physical chunk c_p at row r holds logical chunk (c_p - (r>>1))&3.
// Staging (GLDS16, lane covers row base+(lane>>2), phys chunk lane&3):
//   scol = (((lane&3) - ((lane>>3)&3)) & 3) * 8      [valid: base row multiple of 16]
// Read (logical chunk q at row wr+i*16+fr, wr mult of 32):
//   pcs  = ((q + (fr>>1)) & 3) * 8

// ---------------------------------------------------------------- weight prep
__global__ __launch_bounds__(256) void wprep_kernel(
    const float* __restrict__ W, int K, int N, int Kp,
    unsigned short* __restrict__ Wh, unsigned short* __restrict__ Wl)
{
    int idx = blockIdx.x * 256 + threadIdx.x;
    if (idx >= N * Kp) return;
    int n = idx / Kp, k = idx % Kp;
    float v = (k < K) ? W[(size_t)k * N + n] : 0.f;
    unsigned short h = f2bf(v);
    Wh[idx] = h;
    if (Wl) Wl[idx] = f2bf(v - bf2f(h));
}

// ---------------------------------------------------------------- PLR encode (bf16 hi/lo out)
__global__ __launch_bounds__(256) void plr_bf16_kernel(
    const float* __restrict__ xn_, const float* __restrict__ xc_, int nrows,
    const float* __restrict__ freq, const float* __restrict__ plr_w,
    const float* __restrict__ plr_b,
    unsigned short* __restrict__ oh, unsigned short* __restrict__ ol)
{
    __shared__ float sW[32 * 16];
    __shared__ float sB[16];
    __shared__ float sF[NFEAT * NFREQ];
    int tid = threadIdx.x;
    for (int i = tid; i < 512; i += 256) sW[i] = plr_w[i];
    if (tid < 16) sB[tid] = plr_b[tid];
    for (int i = tid; i < NFEAT * NFREQ; i += 256) sF[i] = freq[i];
    __syncthreads();
    int wave = tid >> 6, lane = tid & 63;
    int row = blockIdx.x * 4 + wave;
    if (row >= nrows) return;
    const float* xn = xn_ + (size_t)row * NFEAT;
    const float* xc = xc_ + (size_t)row * NCAT;
    unsigned short* ph = oh + (size_t)row * KP_IN;
    unsigned short* pl = ol + (size_t)row * KP_IN;
    if (lane < NFEAT) {
        float x = xn[lane];
        float cs[NFREQ], sn[NFREQ];
        #pragma unroll
        for (int j = 0; j < NFREQ; j++) {
            float p = 6.28318530717958647692f * sF[lane * NFREQ + j] * x;
            sn[j] = __sinf(p);
            cs[j] = __cosf(p);
        }
        #pragma unroll
        for (int d = 0; d < DEMB; d++) {
            float acc = sB[d];
            #pragma unroll
            for (int j = 0; j < NFREQ; j++)
                acc = fmaf(cs[j], sW[j * DEMB + d], fmaf(sn[j], sW[(NFREQ + j) * DEMB + d], acc));
            float v = fmaxf(acc, 0.f);
            unsigned short h = f2bf(v);
            ph[lane * DEMB + d] = h;
            pl[lane * DEMB + d] = f2bf(v - bf2f(h));
        }
    }
    if (lane < NCAT) {
        float v = xc[lane];
        unsigned short h = f2bf(v);
        ph[800 + lane] = h;
        pl[800 + lane] = f2bf(v - bf2f(h));
    }
    if (lane >= NCAT && lane < 32) {
        ph[800 + lane] = 0;
        pl[800 + lane] = 0;
    }
}

// ------------------------------- bf16 MFMA GEMM (plain 1-term), 128 tile, 512 threads
__global__ __launch_bounds__(512) void bgemm_kernel(
    const unsigned short* __restrict__ A, const unsigned short* __restrict__ Bt,
    int M, int N, int Kp,
    float* __restrict__ Cf, unsigned short* __restrict__ Cb,
    const float* __restrict__ bias, int flags)
{
    __shared__ unsigned short As[128 * 32];
    __shared__ unsigned short Bs[128 * 32];
    int tid = threadIdx.x;
    int w = tid >> 6, lane = tid & 63;
    int m0 = blockIdx.y * 128, n0 = blockIdx.x * 128;
    int wr = (w >> 1) * 32, wc = (w & 1) * 64;

    f32x4 acc[2][4];
    #pragma unroll
    for (int i = 0; i < 2; i++)
        #pragma unroll
        for (int j = 0; j < 4; j++) acc[i][j] = (f32x4){0.f, 0.f, 0.f, 0.f};

    int arr = w & 1;
    int qrt = (w >> 1) * 32;
    int scol = (((lane & 3) - ((lane >> 3) & 3)) & 3) * 8;
    const unsigned short* gsrc = arr ? Bt : A;
    int glim = arr ? (N - 1) : (M - 1);
    int gb   = arr ? n0 : m0;
    unsigned short* ldst = arr ? Bs : As;
    const unsigned short* gp0 = gsrc + (size_t)min(gb + qrt + (lane >> 2),      glim) * Kp + scol;
    const unsigned short* gp1 = gsrc + (size_t)min(gb + qrt + 16 + (lane >> 2), glim) * Kp + scol;
    unsigned short* lp0 = ldst + qrt * 32;
    unsigned short* lp1 = ldst + (qrt + 16) * 32;

    int fr = lane & 15, q = lane >> 4;
    int pcs = ((q + (fr >> 1)) & 3) * 8;

    for (int k0 = 0; k0 < Kp; k0 += 32) {
        __syncthreads();
        GLDS16(gp0 + k0, lp0);
        GLDS16(gp1 + k0, lp1);
        __syncthreads();
        short8 a[2], b[4];
        #pragma unroll
        for (int i = 0; i < 2; i++)
            a[i] = *(const short8*)&As[(wr + i * 16 + fr) * 32 + pcs];
        #pragma unroll
        for (int j = 0; j < 4; j++)
            b[j] = *(const short8*)&Bs[(wc + j * 16 + fr) * 32 + pcs];
        #pragma unroll
        for (int i = 0; i < 2; i++)
            #pragma unroll
            for (int j = 0; j < 4; j++)
                acc[i][j] = __builtin_amdgcn_mfma_f32_16x16x32_bf16(a[i], b[j], acc[i][j], 0, 0, 0);
    }

    int col = lane & 15, rq = (lane >> 4) * 4;
    #pragma unroll
    for (int i = 0; i < 2; i++)
        #pragma unroll
        for (int j = 0; j < 4; j++) {
            int n_g = n0 + wc + j * 16 + col;
            #pragma unroll
            for (int r = 0; r < 4; r++) {
                int m_g = m0 + wr + i * 16 + rq + r;
                if (m_g < M && n_g < N) {
                    float v = acc[i][j][r];
                    if (bias) v += bias[n_g];
                    if (flags & BG_RELU) v = fmaxf(v, 0.f);
                    if (Cf) Cf[(size_t)m_g * N + n_g] = v;
                    if (Cb) Cb[(size_t)m_g * N + n_g] = f2bf(v);
                }
            }
        }
}

// ------------------------- bf16 MFMA GEMM, 3-term split, 128 tile, 512 threads
__global__ __launch_bounds__(512) void bgemm3_kernel(
    const unsigned short* __restrict__ Ah, const unsigned short* __restrict__ Al,
    const unsigned short* __restrict__ Bh, const unsigned short* __restrict__ Bl,
    int M, int N, int Kp,
    float* __restrict__ Cf, unsigned short* __restrict__ Cbh, unsigned short* __restrict__ Cbl,
    const float* __restrict__ bias, const float* __restrict__ resf,
    const float* __restrict__ cnorm, int flags)
{
    __shared__ unsigned short Ash[128 * 32];
    __shared__ unsigned short Asl[128 * 32];
    __shared__ unsigned short Bsh[128 * 32];
    __shared__ unsigned short Bsl[128 * 32];
    int tid = threadIdx.x;
    int w = tid >> 6, lane = tid & 63;
    int m0 = blockIdx.y * 128, n0 = blockIdx.x * 128;
    int wr = (w >> 1) * 32, wc = (w & 1) * 64;

    f32x4 acc[2][4];
    #pragma unroll
    for (int i = 0; i < 2; i++)
        #pragma unroll
        for (int j = 0; j < 4; j++) acc[i][j] = (f32x4){0.f, 0.f, 0.f, 0.f};

    int arr = w & 3;
    int half = (w >> 2) * 64;
    int scol = (((lane & 3) - ((lane >> 3) & 3)) & 3) * 8;
    const unsigned short* gsrc = (arr == 0) ? Ah : (arr == 1) ? Al : (arr == 2) ? Bh : Bl;
    int glim = (arr < 2) ? (M - 1) : (N - 1);
    int gb   = (arr < 2) ? m0 : n0;
    unsigned short* ldst = (arr == 0) ? Ash : (arr == 1) ? Asl : (arr == 2) ? Bsh : Bsl;
    const unsigned short* gp[4];
    unsigned short* lp[4];
    #pragma unroll
    for (int t = 0; t < 4; t++) {
        int r = half + t * 16;
        gp[t] = gsrc + (size_t)min(gb + r + (lane >> 2), glim) * Kp + scol;
        lp[t] = ldst + r * 32;
    }

    int fr = lane & 15, q = lane >> 4;
    int pcs = ((q + (fr >> 1)) & 3) * 8;

    for (int k0 = 0; k0 < Kp; k0 += 32) {
        __syncthreads();
        GLDS16(gp[0] + k0, lp[0]);
        GLDS16(gp[1] + k0, lp[1]);
        GLDS16(gp[2] + k0, lp[2]);
        GLDS16(gp[3] + k0, lp[3]);
        __syncthreads();
        short8 a[2], b[4];
        #pragma unroll
        for (int i = 0; i < 2; i++)
            a[i] = *(const short8*)&Ash[(wr + i * 16 + fr) * 32 + pcs];
        #pragma unroll
        for (int j = 0; j < 4; j++)
            b[j] = *(const short8*)&Bsh[(wc + j * 16 + fr) * 32 + pcs];
        #pragma unroll
        for (int i = 0; i < 2; i++)
            #pragma unroll
            for (int j = 0; j < 4; j++)
                acc[i][j] = __builtin_amdgcn_mfma_f32_16x16x32_bf16(a[i], b[j], acc[i][j], 0, 0, 0);
        short8 al2[2];
        #pragma unroll
        for (int i = 0; i < 2; i++)
            al2[i] = *(const short8*)&Asl[(wr + i * 16 + fr) * 32 + pcs];
        #pragma unroll
        for (int i = 0; i < 2; i++)
            #pragma unroll
            for (int j = 0; j < 4; j++)
                acc[i][j] = __builtin_amdgcn_mfma_f32_16x16x32_bf16(al2[i], b[j], acc[i][j], 0, 0, 0);
        short8 bl2[4];
        #pragma unroll
        for (int j = 0; j < 4; j++)
            bl2[j] = *(const short8*)&Bsl[(wc + j * 16 + fr) * 32 + pcs];
        #pragma unroll
        for (int i = 0; i < 2; i++)
            #pragma unroll
            for (int j = 0; j < 4; j++)
                acc[i][j] = __builtin_amdgcn_mfma_f32_16x16x32_bf16(a[i], bl2[j], acc[i][j], 0, 0, 0);
    }

    int col = lane & 15, rq = (lane >> 4) * 4;
    #pragma unroll
    for (int i = 0; i < 2; i++)
        #pragma unroll
        for (int j = 0; j < 4; j++) {
            int n_g = n0 + wc + j * 16 + col;
            #pragma unroll
            for (int r = 0; r < 4; r++) {
                int m_g = m0 + wr + i * 16 + rq + r;
                if (m_g < M && n_g < N) {
                    float v = acc[i][j][r];
                    if (bias) v += bias[n_g];
                    if (resf) v += resf[(size_t)m_g * N + n_g];
                    if (flags & BG_RELU) v = fmaxf(v, 0.f);
                    if (flags & BG_SCORE) v = 2.f * v - cnorm[n_g];
                    if (Cf) Cf[(size_t)m_g * N + n_g] = v;
                    if (Cbh) {
                        unsigned short h = f2bf(v);
                        Cbh[(size_t)m_g * N + n_g] = h;
                        if (Cbl) Cbl[(size_t)m_g * N + n_g] = f2bf(v - bf2f(h));
                    }
                }
            }
        }
}

// ------------------------- small-M GEMM: 64x64 tile, 1- or 3-term (Al null => 1-term)
__global__ __launch_bounds__(256) void bgemm3s_kernel(
    const unsigned short* __restrict__ Ah, const unsigned short* __restrict__ Al,
    const unsigned short* __restrict__ Bh, const unsigned short* __restrict__ Bl,
    int M, int N, int Kp,
    float* __restrict__ Cf, unsigned short* __restrict__ Cbh, unsigned short* __restrict__ Cbl,
    const float* __restrict__ bias, const float* __restrict__ resf, int flags)
{
    __shared__ unsigned short Ash[64 * 32];
    __shared__ unsigned short Asl[64 * 32];
    __shared__ unsigned short Bsh[64 * 32];
    __shared__ unsigned short Bsl[64 * 32];
    int tid = threadIdx.x;
    int w = tid >> 6, lane = tid & 63;
    int m0 = blockIdx.y * 64, n0 = blockIdx.x * 64;
    int wr = (w >> 1) * 32, wc = (w & 1) * 32;
    int three = (Al != nullptr);

    f32x4 acc[2][2];
    #pragma unroll
    for (int i = 0; i < 2; i++)
        #pragma unroll
        for (int j = 0; j < 2; j++) acc[i][j] = (f32x4){0.f, 0.f, 0.f, 0.f};

    int srow = w * 16 + (lane >> 2);
    int scol = (((lane & 3) - ((lane >> 3) & 3)) & 3) * 8;
    size_t ra = (size_t)min(m0 + srow, M - 1) * Kp + scol;
    size_t rb = (size_t)min(n0 + srow, N - 1) * Kp + scol;
    unsigned short* lah = &Ash[(w * 16) * 32];
    unsigned short* lal = &Asl[(w * 16) * 32];
    unsigned short* lbh = &Bsh[(w * 16) * 32];
    unsigned short* lbl = &Bsl[(w * 16) * 32];

    int fr = lane & 15, q = lane >> 4;
    int pcs = ((q + (fr >> 1)) & 3) * 8;

    for (int k0 = 0; k0 < Kp; k0 += 32) {
        __syncthreads();
        GLDS16(Ah + ra + k0, lah);
        GLDS16(Bh + rb + k0, lbh);
        if (three) {
            GLDS16(Al + ra + k0, lal);
            GLDS16(Bl + rb + k0, lbl);
        }
        __syncthreads();
        short8 a[2], b[2];
        #pragma unroll
        for (int i = 0; i < 2; i++)
            a[i] = *(const short8*)&Ash[(wr + i * 16 + fr) * 32 + pcs];
        #pragma unroll
        for (int j = 0; j < 2; j++)
            b[j] = *(const short8*)&Bsh[(wc + j * 16 + fr) * 32 + pcs];
        #pragma unroll
        for (int i = 0; i < 2; i++)
            #pragma unroll
            for (int j = 0; j < 2; j++)
                acc[i][j] = __builtin_amdgcn_mfma_f32_16x16x32_bf16(a[i], b[j], acc[i][j], 0, 0, 0);
        if (three) {
            short8 al2[2], bl2[2];
            #pragma unroll
            for (int i = 0; i < 2; i++)
                al2[i] = *(const short8*)&Asl[(wr + i * 16 + fr) * 32 + pcs];
            #pragma unroll
            for (int j = 0; j < 2; j++)
                bl2[j] = *(const short8*)&Bsl[(wc + j * 16 + fr) * 32 + pcs];
            #pragma unroll
            for (int i = 0; i < 2; i++)
                #pragma unroll
                for (int j = 0; j < 2; j++) {
                    acc[i][j] = __builtin_amdgcn_mfma_f32_16x16x32_bf16(al2[i], b[j], acc[i][j], 0, 0, 0);
                    acc[i][j] = __builtin_amdgcn_mfma_f32_16x16x32_bf16(a[i], bl2[j], acc[i][j], 0, 0, 0);
                }
        }
    }

    int col = lane & 15, rq = (lane >> 4) * 4;
    #pragma unroll
    for (int i = 0; i < 2; i++)
        #pragma unroll
        for (int j = 0; j < 2; j++) {
            int n_g = n0 + wc + j * 16 + col;
            #pragma unroll
            for (int r = 0; r < 4; r++) {
                int m_g = m0 + wr + i * 16 + rq + r;
                if (m_g < M && n_g < N) {
                    float v = acc[i][j][r];
                    if (bias) v += bias[n_g];
                    if (resf) v += resf[(size_t)m_g * N + n_g];
                    if (flags & BG_RELU) v = fmaxf(v, 0.f);
                    if (Cf) Cf[(size_t)m_g * N + n_g] = v;
                    if (Cbh) {
                        unsigned short h = f2bf(v);
                        Cbh[(size_t)m_g * N + n_g] = h;
                        if (Cbl) Cbl[(size_t)m_g * N + n_g] = f2bf(v - bf2f(h));
                    }
                }
            }
        }
}

// ---------------------------------------------------------------- LayerNorm bf16 hi/lo out
__global__ __launch_bounds__(256) void ln_split_kernel(const float* __restrict__ X,
    unsigned short* __restrict__ Yh, unsigned short* __restrict__ Yl,
    const float* __restrict__ g, const float* __restrict__ bt, int M)
{
    int wave = threadIdx.x >> 6, lane = threadIdx.x & 63;
    int row = blockIdx.x * 4 + wave;
    if (row >= M) return;
    const float* x = X + (size_t)row * DM;
    float4 v0 = ((const float4*)x)[lane * 2];
    float4 v1 = ((const float4*)x)[lane * 2 + 1];
    float s = v0.x + v0.y + v0.z + v0.w + v1.x + v1.y + v1.z + v1.w;
    #pragma unroll
    for (int off = 32; off; off >>= 1) s += __shfl_xor(s, off, 64);
    float m = s * (1.f / DM);
    float q = (v0.x - m) * (v0.x - m) + (v0.y - m) * (v0.y - m)
            + (v0.z - m) * (v0.z - m) + (v0.w - m) * (v0.w - m)
            + (v1.x - m) * (v1.x - m) + (v1.y - m) * (v1.y - m)
            + (v1.z - m) * (v1.z - m) + (v1.w - m) * (v1.w - m);
    #pragma unroll
    for (int off = 32; off; off >>= 1) q += __shfl_xor(q, off, 64);
    float rstd = 1.f / sqrtf(q * (1.f / DM) + 1e-5f);
    float vals[8] = {v0.x, v0.y, v0.z, v0.w, v1.x, v1.y, v1.z, v1.w};
    unsigned short* yh = Yh + (size_t)row * DM + lane * 8;
    unsigned short* yl = Yl + (size_t)row * DM + lane * 8;
    const float* gp = g + lane * 8;
    const float* bp = bt + lane * 8;
    #pragma unroll
    for (int i = 0; i < 8; i++) {
        float y = (vals[i] - m) * rstd * gp[i] + bp[i];
        unsigned short h = f2bf(y);
        yh[i] = h;
        yl[i] = f2bf(y - bf2f(h));
    }
}

// ---------------------------------------------------------------- key norms (fp32 k)
__global__ __launch_bounds__(256) void cnorm_kernel(const float* __restrict__ Kc,
    float* __restrict__ cn, int N)
{
    int wave = threadIdx.x >> 6, lane = threadIdx.x & 63;
    int row = blockIdx.x * 4 + wave;
    if (row >= N) return;
    const float* x = Kc + (size_t)row * DM;
    float4 v0 = ((const float4*)x)[lane * 2];
    float4 v1 = ((const float4*)x)[lane * 2 + 1];
    float s = v0.x * v0.x + v0.y * v0.y + v0.z * v0.z + v0.w * v0.w
            + v1.x * v1.x + v1.y * v1.y + v1.z * v1.z + v1.w * v1.w;
    #pragma unroll
    for (int off = 32; off; off >>= 1) s += __shfl_xor(s, off, 64);
    if (lane == 0) cn[row] = s;
}

// ---------------------------------------------------------------- ctx init
__global__ void ctx_init_kernel(int* __restrict__ idx, float* __restrict__ sc)
{
    int i = blockIdx.x * 256 + threadIdx.x;
    if (i < NB * CTX) { idx[i] = 0; sc[i] = -1e30f; }
}

// ------------------------------------- running top-96 merge: exact radix select
// Deterministic: selection set defined by (score desc, global idx asc) total order.
#define CANDCAP 2048
__global__ __launch_bounds__(256) void topk_merge_kernel(
    const float* __restrict__ S, int m, int base,
    const int* __restrict__ pidx, const float* __restrict__ pscore,
    int* __restrict__ nidx, float* __restrict__ nscore)
{
    __shared__ unsigned int hist[256];
    __shared__ unsigned int s_prefix;
    __shared__ int s_above;
    __shared__ float prev_s[CTX];
    __shared__ int   prev_i[CTX];
    __shared__ int   nsel, neq;
    __shared__ float sel_s[CTX];
    __shared__ int   sel_g[CTX];
    __shared__ int   cnd_g[CANDCAP];

    int b = blockIdx.x, tid = threadIdx.x;
    const float* Sb = S + (size_t)b * m;
    if (tid < CTX) { prev_s[tid] = pscore[b * CTX + tid]; prev_i[tid] = pidx[b * CTX + tid]; }
    if (tid == 0) { s_prefix = 0u; s_above = 0; nsel = 0; neq = 0; }
    int tot = m + CTX;
    __syncthreads();

    // 4 radix passes, MSB-first, on order-preserving uint key
    for (int pass = 0; pass < 4; pass++) {
        int shift = 24 - pass * 8;
        for (int i = tid; i < 256; i += 256) hist[i] = 0;
        __syncthreads();
        unsigned int pref = s_prefix;
        unsigned int mask = (pass == 0) ? 0u : (0xFFFFFFFFu << (32 - 8 * pass));
        for (int i = tid; i < tot; i += 256) {
            float v = (i < m) ? Sb[i] : prev_s[i - m];
            unsigned int k = f2key(v);
            if ((k & mask) == pref) atomicAdd(&hist[(k >> shift) & 255], 1u);
        }
        __syncthreads();
        if (tid == 0) {
            int above = s_above, bsel = 0;
            for (int i2 = 255; i2 >= 0; i2--) {
                int h = (int)hist[i2];
                if (above + h >= CTX) { bsel = i2; break; }
                above += h;
            }
            s_above = above;
            s_prefix = pref | ((unsigned int)bsel << shift);
        }
        __syncthreads();
    }
    unsigned int thrK = s_prefix;
    int msel = CTX - s_above;          // take msel among key==thrK by smallest idx
    float eqv = key2f(thrK);

    // collect: strictly above threshold -> selected; equal -> candidates
    for (int i = tid; i < tot; i += 256) {
        float v = (i < m) ? Sb[i] : prev_s[i - m];
        unsigned int k = f2key(v);
        if (k < thrK) continue;
        int g = (i < m) ? (base + i) : prev_i[i - m];
        if (k > thrK) {
            int p = atomicAdd(&nsel, 1);
            sel_s[p] = v; sel_g[p] = g;
        } else {
            int p = atomicAdd(&neq, 1);
            if (p < CANDCAP) cnd_g[p] = g;
        }
    }
    __syncthreads();
    int ne = neq;
    if (ne <= CANDCAP) {
        for (int i = tid; i < ne; i += 256) {
            int gi = cnd_g[i];
            int rank = 0;
            for (int j = 0; j < ne; j++) rank += (cnd_g[j] < gi);
            if (rank < msel) {
                int p = atomicAdd(&nsel, 1);
                sel_s[p] = eqv; sel_g[p] = gi;
            }
        }
    } else {
        // pathological mass-tie fallback: deterministic idx-rank via full scan
        for (int i = tid; i < tot; i += 256) {
            float v = (i < m) ? Sb[i] : prev_s[i - m];
            if (f2key(v) != thrK) continue;
            int g = (i < m) ? (base + i) : prev_i[i - m];
            int rank = 0;
            for (int j = 0; j < tot; j++) {
                float vj = (j < m) ? Sb[j] : prev_s[j - m];
                if (f2key(vj) == thrK) {
                    int gj = (j < m) ? (base + j) : prev_i[j - m];
                    rank += (gj < g);
                }
            }
            if (rank < msel) {
                int p = atomicAdd(&nsel, 1);
                sel_s[p] = eqv; sel_g[p] = g;
            }
        }
    }
    __syncthreads();
    if (tid < CTX) {
        nidx[b * CTX + tid] = sel_g[tid];
        nscore[b * CTX + tid] = sel_s[tid];
    }
}

// ------------------------------- softmax + label/value context aggregation
__global__ __launch_bounds__(256) void agg_kernel(
    const int* __restrict__ ctx_idx, const float* __restrict__ ctx_score,
    const float* __restrict__ cand_y, const float* __restrict__ T1b,
    const unsigned short* __restrict__ T1c, const float* __restrict__ T_b1,
    const float* __restrict__ x_batch,
    const float* __restrict__ label_w, const float* __restrict__ label_b,
    unsigned short* __restrict__ s_h, unsigned short* __restrict__ s_l,
    float* __restrict__ u_out)
{
    __shared__ float p_s[CTX];
    __shared__ int   p_i[CTX];
    __shared__ float s_ybar;
    int b = blockIdx.x, tid = threadIdx.x;
    if (tid < CTX) { p_s[tid] = ctx_score[b * CTX + tid]; p_i[tid] = ctx_idx[b * CTX + tid]; }
    __syncthreads();
    if (tid == 0) {
        float mx = -1e30f;
        for (int c = 0; c < CTX; c++) mx = fmaxf(mx, p_s[c]);
        float sum = 0.f;
        for (int c = 0; c < CTX; c++) { float e = __expf(p_s[c] - mx); p_s[c] = e; sum += e; }
        float inv = 1.f / sum, yb = 0.f;
        for (int c = 0; c < CTX; c++) { p_s[c] *= inv; yb += p_s[c] * cand_y[p_i[c]]; }
        s_ybar = yb;
    }
    __syncthreads();
    int j = tid * 4;
    float4 kv = *(const float4*)(T1b + (size_t)b * DBK + j);
    float4 tb = *(const float4*)(T_b1 + j);
    float base0 = kv.x + tb.x, base1 = kv.y + tb.y, base2 = kv.z + tb.z, base3 = kv.w + tb.w;
    float a0 = 0.f, a1 = 0.f, a2 = 0.f, a3 = 0.f;
    for (int c = 0; c < CTX; c++) {
        float p = p_s[c];
        ushort4 cu = *(const ushort4*)(T1c + (size_t)p_i[c] * DBK + j);
        a0 = fmaf(p, fmaxf(base0 - bf2f(cu.x), 0.f), a0);
        a1 = fmaf(p, fmaxf(base1 - bf2f(cu.y), 0.f), a1);
        a2 = fmaf(p, fmaxf(base2 - bf2f(cu.z), 0.f), a2);
        a3 = fmaf(p, fmaxf(base3 - bf2f(cu.w), 0.f), a3);
    }
    {
        ushort4 oh, ol;
        oh.x = f2bf(a0); ol.x = f2bf(a0 - bf2f(oh.x));
        oh.y = f2bf(a1); ol.y = f2bf(a1 - bf2f(oh.y));
        oh.z = f2bf(a2); ol.z = f2bf(a2 - bf2f(oh.z));
        oh.w = f2bf(a3); ol.w = f2bf(a3 - bf2f(oh.w));
        *(ushort4*)(s_h + (size_t)b * DBK + j) = oh;
        *(ushort4*)(s_l + (size_t)b * DBK + j) = ol;
    }
    if (tid < 128) {
        int d = tid * 4;
        float4 xv = *(const float4*)(x_batch + (size_t)b * DM + d);
        float4 lw = *(const float4*)(label_w + d);
        float4 lb = *(const float4*)(label_b + d);
        float yb = s_ybar;
        *(float4*)(u_out + (size_t)b * DM + d) =
            make_float4(xv.x + yb * lw.x + lb.x, xv.y + yb * lw.y + lb.y,
                        xv.z + yb * lw.z + lb.z, xv.w + yb * lw.w + lb.w);
    }
}

// ---------------------------------------------------------------- head
__global__ __launch_bounds__(256) void head_kernel(
    const float* __restrict__ X, const float* __restrict__ g,
    const float* __restrict__ bt, const float* __restrict__ w,
    const float* __restrict__ hb, float* __restrict__ out, int M)
{
    int wave = threadIdx.x >> 6, lane = threadIdx.x & 63;
    int row = blockIdx.x * 4 + wave;
    if (row >= M) return;
    const float* x = X + (size_t)row * DM;
    float4 v0 = ((const float4*)x)[lane * 2];
    float4 v1 = ((const float4*)x)[lane * 2 + 1];
    float s = v0.x + v0.y + v0.z + v0.w + v1.x + v1.y + v1.z + v1.w;
    #pragma unroll
    for (int off = 32; off; off >>= 1) s += __shfl_xor(s, off, 64);
    float m = s * (1.f / DM);
    float q = (v0.x - m) * (v0.x - m) + (v0.y - m) * (v0.y - m)
            + (v0.z - m) * (v0.z - m) + (v0.w - m) * (v0.w - m)
            + (v1.x - m) * (v1.x - m) + (v1.y - m) * (v1.y - m)
            + (v1.z - m) * (v1.z - m) + (v1.w - m) * (v1.w - m);
    #pragma unroll
    for (int off = 32; off; off >>= 1) q += __shfl_xor(q, off, 64);
    float rstd = 1.f / sqrtf(q * (1.f / DM) + 1e-5f);
    float4 g0 = ((const float4*)g)[lane * 2], g1 = ((const float4*)g)[lane * 2 + 1];
    float4 b0 = ((const float4*)bt)[lane * 2], b1 = ((const float4*)bt)[lane * 2 + 1];
    float4 w0 = ((const float4*)w)[lane * 2], w1 = ((const float4*)w)[lane * 2 + 1];
    float t = 0.f;
    t += fmaxf((v0.x - m) * rstd * g0.x + b0.x, 0.f) * w0.x;
    t += fmaxf((v0.y - m) * rstd * g0.y + b0.y, 0.f) * w0.y;
    t += fmaxf((v0.z - m) * rstd * g0.z + b0.z, 0.f) * w0.z;
    t += fmaxf((v0.w - m) * rstd * g0.w + b0.w, 0.f) * w0.w;
    t += fmaxf((v1.x - m) * rstd * g1.x + b1.x, 0.f) * w1.x;
    t += fmaxf((v1.y - m) * rstd * g1.y + b1.y, 0.f) * w1.y;
    t += fmaxf((v1.z - m) * rstd * g1.z + b1.z, 0.f) * w1.z;
    t += fmaxf((v1.w - m) * rstd * g1.w + b1.w, 0.f) * w1.w;
    #pragma unroll
    for (int off = 32; off; off >>= 1) t += __shfl_xor(t, off, 64);
    if (lane == 0) out[row] = t + hb[0];
}

// =================================================================== host
extern "C" void kernel_launch(void* const* d_in, const int* in_sizes, int n_in,
                              void* d_out, int out_size, void* d_ws, size_t ws_size,
                              hipStream_t stream) {
    (void)in_sizes; (void)n_in; (void)out_size;
    const float* x_num   = (const float*)d_in[0];
    const float* x_cat   = (const float*)d_in[1];
    const float* cxn     = (const float*)d_in[2];
    const float* cxc     = (const float*)d_in[3];
    const float* cand_y  = (const float*)d_in[4];
    const float* freq    = (const float*)d_in[6];
    const float* plr_w   = (const float*)d_in[7];
    const float* plr_b   = (const float*)d_in[8];
    const float* lin_w   = (const float*)d_in[9];
    const float* lin_b   = (const float*)d_in[10];
    const float* enc_w1  = (const float*)d_in[11];
    const float* enc_b1  = (const float*)d_in[12];
    const float* enc_w2  = (const float*)d_in[13];
    const float* enc_b2  = (const float*)d_in[14];
    const float* mix_g   = (const float*)d_in[15];
    const float* mix_b   = (const float*)d_in[16];
    const float* K_w     = (const float*)d_in[17];
    const float* K_b     = (const float*)d_in[18];
    const float* label_w = (const float*)d_in[19];
    const float* label_b = (const float*)d_in[20];
    const float* T_w1    = (const float*)d_in[21];
    const float* T_b1    = (const float*)d_in[22];
    const float* T_w2    = (const float*)d_in[23];
    const float* pred_g  = (const float*)d_in[24];
    const float* pred_b  = (const float*)d_in[25];
    const float* pred_w1 = (const float*)d_in[26];
    const float* pred_b1 = (const float*)d_in[27];
    const float* pred_w2 = (const float*)d_in[28];
    const float* pred_b2 = (const float*)d_in[29];
    const float* head_g  = (const float*)d_in[30];
    const float* head_b  = (const float*)d_in[31];
    const float* head_w  = (const float*)d_in[32];
    const float* head_bias = (const float*)d_in[33];
    float* out = (float*)d_out;

    char* ws = (char*)d_ws;
    size_t off = 0;
    auto alloc = [&](size_t n) { char* p = ws + off; off = (off + n + 255) & ~(size_t)255; return p; };

    typedef unsigned short u16;
    // --- bf16 weights (transposed to N x Kp), hi/lo ---
    u16* lin_wt_h = (u16*)alloc((size_t)DM * KP_IN * 2);
    u16* lin_wt_l = (u16*)alloc((size_t)DM * KP_IN * 2);
    u16* e1t_h    = (u16*)alloc((size_t)DBK * DM * 2);
    u16* e1t_l    = (u16*)alloc((size_t)DBK * DM * 2);
    u16* e2t_h    = (u16*)alloc((size_t)DM * DBK * 2);
    u16* e2t_l    = (u16*)alloc((size_t)DM * DBK * 2);
    u16* K_wt_h   = (u16*)alloc((size_t)DM * DM * 2);
    u16* K_wt_l   = (u16*)alloc((size_t)DM * DM * 2);
    u16* T_w1t    = (u16*)alloc((size_t)DBK * DM * 2);
    u16* T_w2t_h  = (u16*)alloc((size_t)DM * DBK * 2);
    u16* T_w2t_l  = (u16*)alloc((size_t)DM * DBK * 2);
    u16* p1t_h    = (u16*)alloc((size_t)DBK * DM * 2);
    u16* p1t_l    = (u16*)alloc((size_t)DBK * DM * 2);
    u16* p2t_h    = (u16*)alloc((size_t)DM * DBK * 2);
    u16* p2t_l    = (u16*)alloc((size_t)DM * DBK * 2);
    // --- persistent ---
    u16*   T1c  = (u16*)alloc((size_t)NCAND * DBK * 2);   // 102.4 MB
    float* T1b  = (float*)alloc((size_t)NB * DBK * 4);
    float* xB   = (float*)alloc((size_t)NB * DM * 4);
    u16*   kBh  = (u16*)alloc((size_t)NB * DM * 2);
    u16*   kBl  = (u16*)alloc((size_t)NB * DM * 2);
    // batch scratch
    u16* binh = (u16*)alloc((size_t)NB * KP_IN * 2);
    u16* binl = (u16*)alloc((size_t)NB * KP_IN * 2);
    u16* xBhh = (u16*)alloc((size_t)NB * DM * 2);
    u16* xBhl = (u16*)alloc((size_t)NB * DM * 2);
    u16* hBh  = (u16*)alloc((size_t)NB * DBK * 2);
    u16* hBl  = (u16*)alloc((size_t)NB * DBK * 2);
    u16* lnBh = (u16*)alloc((size_t)NB * DM * 2);
    u16* lnBl = (u16*)alloc((size_t)NB * DM * 2);
    // ctx + tail
    int*   ctxAi = (int*)alloc((size_t)NB * CTX * 4);
    float* ctxAs = (float*)alloc((size_t)NB * CTX * 4);
    int*   ctxBi = (int*)alloc((size_t)NB * CTX * 4);
    float* ctxBs = (float*)alloc((size_t)NB * CTX * 4);
    u16*   sbufh = (u16*)alloc((size_t)NB * DBK * 2);
    u16*   sbufl = (u16*)alloc((size_t)NB * DBK * 2);
    float* ubuf  = (float*)alloc((size_t)NB * DM * 4);
    float* x2    = (float*)alloc((size_t)NB * DM * 4);
    u16*   h2h   = (u16*)alloc((size_t)NB * DM * 2);
    u16*   h2l   = (u16*)alloc((size_t)NB * DM * 2);
    u16*   hph   = (u16*)alloc((size_t)NB * DBK * 2);
    u16*   hpl   = (u16*)alloc((size_t)NB * DBK * 2);
    float* x3    = (float*)alloc((size_t)NB * DM * 4);

    // --- chunk arenas with lifetime-based aliasing (11.5 KB/row) ---
    size_t remain = (ws_size > off + 8192) ? (ws_size - off - 8192) : 0;
    const size_t perrow = 3328 + 2048 + 2048 + 4096 + 64;
    long ncl = (long)(remain / perrow);
    int NC = (int)(ncl > 25600 ? 25600 : ncl);
    NC &= ~127;
    if (NC < 256) NC = 256;
    char* arenaA = alloc((size_t)NC * 3328);   // inCh+inCl -> kC + cnC
    char* arenaB = alloc((size_t)NC * 2048);   // xC -> scoresC
    char* arenaC = alloc((size_t)NC * 2048);   // xCh/xCl -> lnCh/lnCl
    char* arenaD = alloc((size_t)NC * 4096);   // hCh/hCl -> kCh/kCl
    u16* inCh = (u16*)arenaA;
    u16* inCl = inCh + (size_t)NC * KP_IN;
    float* kC  = (float*)arenaA;                       // after lin: inC dead
    float* cnC = (float*)(arenaA + (size_t)NC * 2048);
    float* xC  = (float*)arenaB;
    float* scoresC = (float*)arenaB;                   // after ln: xC dead
    u16* xCh  = (u16*)arenaC;
    u16* xCl  = xCh + (size_t)NC * DM;
    u16* lnCh = (u16*)arenaC;                          // after enc1: xCh dead
    u16* lnCl = lnCh + (size_t)NC * DM;
    u16* hCh  = (u16*)arenaD;
    u16* hCl  = hCh + (size_t)NC * DBK;
    u16* kCh  = (u16*)arenaD;                          // after enc2: hC dead
    u16* kCl  = kCh + (size_t)NC * DM;

    auto bgemm = [&](const u16* A, const u16* Bt, int M, int N, int Kp,
                     float* Cf, u16* Cb, const float* bias, int flags) {
        dim3 grid((N + 127) / 128, (M + 127) / 128);
        bgemm_kernel<<<grid, 512, 0, stream>>>(A, Bt, M, N, Kp, Cf, Cb, bias, flags);
    };
    auto bgemm3 = [&](const u16* Ah, const u16* Al, const u16* Bh, const u16* Bl,
                      int M, int N, int Kp, float* Cf, u16* Cbh, u16* Cbl,
                      const float* bias, const float* resf, const float* cnorm, int flags) {
        dim3 grid((N + 127) / 128, (M + 127) / 128);
        bgemm3_kernel<<<grid, 512, 0, stream>>>(Ah, Al, Bh, Bl, M, N, Kp,
                                                Cf, Cbh, Cbl, bias, resf, cnorm, flags);
    };
    auto bgemm3s = [&](const u16* Ah, const u16* Al, const u16* Bh, const u16* Bl,
                       int M, int N, int Kp, float* Cf, u16* Cbh, u16* Cbl,
                       const float* bias, const float* resf, int flags) {
        dim3 grid((N + 63) / 64, (M + 63) / 64);
        bgemm3s_kernel<<<grid, 256, 0, stream>>>(Ah, Al, Bh, Bl, M, N, Kp,
                                                 Cf, Cbh, Cbl, bias, resf, flags);
    };
    auto wprep = [&](const float* W, int K, int N, int Kp, u16* Wh, u16* Wl) {
        int n = N * Kp;
        wprep_kernel<<<(n + 255) / 256, 256, 0, stream>>>(W, K, N, Kp, Wh, Wl);
    };

    // ---------- weight prep ----------
    wprep(lin_w, DIN, DM, KP_IN, lin_wt_h, lin_wt_l);
    wprep(enc_w1, DM, DBK, DM, e1t_h, e1t_l);
    wprep(enc_w2, DBK, DM, DBK, e2t_h, e2t_l);
    wprep(K_w, DM, DM, DM, K_wt_h, K_wt_l);
    wprep(T_w1, DM, DBK, DM, T_w1t, nullptr);
    wprep(T_w2, DBK, DM, DBK, T_w2t_h, T_w2t_l);
    wprep(pred_w1, DM, DBK, DM, p1t_h, p1t_l);
    wprep(pred_w2, DBK, DM, DBK, p2t_h, p2t_l);

    // ---------- batch encode (64-tile split GEMMs) ----------
    plr_bf16_kernel<<<(NB + 3) / 4, 256, 0, stream>>>(x_num, x_cat, NB, freq, plr_w, plr_b, binh, binl);
    bgemm3s(binh, binl, lin_wt_h, lin_wt_l, NB, DM, KP_IN, xB, xBhh, xBhl, lin_b, nullptr, 0);
    bgemm3s(xBhh, xBhl, e1t_h, e1t_l, NB, DBK, DM, nullptr, hBh, hBl, enc_b1, nullptr, BG_RELU);
    bgemm3s(hBh, hBl, e2t_h, e2t_l, NB, DM, DBK, xB, nullptr, nullptr, enc_b2, xB, 0);
    ln_split_kernel<<<(NB + 3) / 4, 256, 0, stream>>>(xB, lnBh, lnBl, mix_g, mix_b, NB);
    bgemm3s(lnBh, lnBl, K_wt_h, K_wt_l, NB, DM, DM, nullptr, kBh, kBl, K_b, nullptr, 0);
    bgemm3s(kBh, nullptr, T_w1t, nullptr, NB, DBK, DM, T1b, nullptr, nullptr, nullptr, nullptr, 0);
    ctx_init_kernel<<<(NB * CTX + 255) / 256, 256, 0, stream>>>(ctxAi, ctxAs);

    // ---------- candidate chunks (128-tile, 512-thread GEMMs) ----------
    const int* pI = ctxAi; const float* pS = ctxAs;
    int* nI = ctxBi; float* nS = ctxBs;
    int nch = (NCAND + NC - 1) / NC;
    for (int c = 0; c < nch; c++) {
        int s = c * NC;
        int m = NCAND - s; if (m > NC) m = NC;
        plr_bf16_kernel<<<(m + 3) / 4, 256, 0, stream>>>(cxn + (size_t)s * NFEAT,
                                                         cxc + (size_t)s * NCAT,
                                                         m, freq, plr_w, plr_b, inCh, inCl);
        bgemm3(inCh, inCl, lin_wt_h, lin_wt_l, m, DM, KP_IN, xC, xCh, xCl, lin_b, nullptr, nullptr, 0);
        bgemm3(xCh, xCl, e1t_h, e1t_l, m, DBK, DM, nullptr, hCh, hCl, enc_b1, nullptr, nullptr, BG_RELU);
        bgemm3(hCh, hCl, e2t_h, e2t_l, m, DM, DBK, xC, nullptr, nullptr, enc_b2, xC, nullptr, 0);
        ln_split_kernel<<<(m + 3) / 4, 256, 0, stream>>>(xC, lnCh, lnCl, mix_g, mix_b, m);
        bgemm3(lnCh, lnCl, K_wt_h, K_wt_l, m, DM, DM, kC, kCh, kCl, K_b, nullptr, nullptr, 0);
        cnorm_kernel<<<(m + 3) / 4, 256, 0, stream>>>(kC, cnC, m);
        bgemm(kCh, T_w1t, m, DBK, DM, nullptr, T1c + (size_t)s * DBK, nullptr, 0);
        bgemm3(kBh, kBl, kCh, kCl, NB, m, DM, scoresC, nullptr, nullptr,
               nullptr, nullptr, cnC, BG_SCORE);
        topk_merge_kernel<<<NB, 256, 0, stream>>>(scoresC, m, s, pI, pS, nI, nS);
        { const int* t = pI; pI = nI; nI = (int*)t; }
        { const float* t = pS; pS = nS; nS = (float*)t; }
    }

    // ---------- aggregation + predictor + head (64-tile split GEMMs) ----------
    agg_kernel<<<NB, 256, 0, stream>>>(pI, pS, cand_y, T1b, T1c, T_b1,
                                       xB, label_w, label_b, sbufh, sbufl, ubuf);
    bgemm3s(sbufh, sbufl, T_w2t_h, T_w2t_l, NB, DM, DBK, x2, nullptr, nullptr,
            nullptr, ubuf, 0);
    ln_split_kernel<<<(NB + 3) / 4, 256, 0, stream>>>(x2, h2h, h2l, pred_g, pred_b, NB);
    bgemm3s(h2h, h2l, p1t_h, p1t_l, NB, DBK, DM, nullptr, hph, hpl, pred_b1, nullptr, BG_RELU);
    bgemm3s(hph, hpl, p2t_h, p2t_l, NB, DM, DBK, x3, nullptr, nullptr, pred_b2, x2, 0);
    head_kernel<<<(NB + 3) / 4, 256, 0, stream>>>(x3, head_g, head_b, head_w, head_bias, out, NB);
}